// Round 1
// baseline (916.193 us; speedup 1.0000x reference)
//
#include <hip/hip_runtime.h>

#define KF 8
#define TN 4
#define SDIM 16
#define EMB 128

// ---------------- per-relation top-k permutation ----------------
__global__ void k_relmap(const float* __restrict__ rel_att, int num_rel,
                         int* __restrict__ posmap, int* __restrict__ topmap) {
    int q = blockIdx.x * blockDim.x + threadIdx.x;
    if (q >= num_rel) return;
    float v[KF]; int idx[KF];
    for (int k = 0; k < KF; ++k) { v[k] = rel_att[q * KF + k]; idx[k] = k; }
    // stable insertion sort, descending (equal keys keep index order == argsort(-att))
    for (int i = 1; i < KF; ++i) {
        float vi = v[i]; int ii = idx[i]; int j = i - 1;
        while (j >= 0 && v[j] < vi) { v[j + 1] = v[j]; idx[j + 1] = idx[j]; --j; }
        v[j + 1] = vi; idx[j + 1] = ii;
    }
    int pos[KF];
    for (int k = 0; k < KF; ++k) pos[k] = -1;
    for (int j = 0; j < TN; ++j) { topmap[q * TN + j] = idx[j]; pos[idx[j]] = j; }
    for (int k = 0; k < KF; ++k) posmap[q * KF + k] = pos[k];
}

// ---------------- histograms ----------------
__global__ void k_hist(const int* __restrict__ tails, const int* __restrict__ types,
                       int nE, int* __restrict__ deg, int* __restrict__ rcnt) {
    int i = blockIdx.x * blockDim.x + threadIdx.x;
    if (i >= nE) return;
    atomicAdd(&deg[tails[i]], 1);
    atomicAdd(&rcnt[types[i]], 1);
}

// ---------------- single-block exclusive scan ----------------
__global__ void k_scan(const int* __restrict__ in, int* __restrict__ out, int n) {
    __shared__ int warp_sums[16];
    int carry = 0;
    int lane = threadIdx.x & 63, wid = threadIdx.x >> 6;
    int nw = blockDim.x >> 6;
    for (int base = 0; base < n; base += blockDim.x) {
        int i = base + (int)threadIdx.x;
        int v = (i < n) ? in[i] : 0;
        int sv = v;
        for (int o = 1; o < 64; o <<= 1) { int t = __shfl_up(sv, o, 64); if (lane >= o) sv += t; }
        if (lane == 63) warp_sums[wid] = sv;
        __syncthreads();
        if (wid == 0 && lane < nw) {
            int ws = warp_sums[lane];
            for (int o = 1; o < 16; o <<= 1) { int t = __shfl_up(ws, o, 64); if (lane >= o) ws += t; }
            warp_sums[lane] = ws;
        }
        __syncthreads();
        int wofs = (wid > 0) ? warp_sums[wid - 1] : 0;
        int total = warp_sums[nw - 1];
        if (i < n) out[i] = carry + wofs + sv - v;
        carry += total;
        __syncthreads();
    }
    if (threadIdx.x == 0) out[n] = carry;
}

// ---------------- CSR scatter ----------------
__global__ void k_scatter(const int* __restrict__ heads, const int* __restrict__ tails,
                          const int* __restrict__ types, int nE,
                          int* __restrict__ tail_cur, int2* __restrict__ tail_edges,
                          int* __restrict__ rel_cur, int2* __restrict__ rel_edges) {
    int i = blockIdx.x * blockDim.x + threadIdx.x;
    if (i >= nE) return;
    int h = heads[i], t = tails[i], q = types[i];
    int p = atomicAdd(&tail_cur[t], 1);
    tail_edges[p] = make_int2(h, q);
    int p2 = atomicAdd(&rel_cur[q], 1);
    rel_edges[p2] = make_int2(t, h);
}

// ---------------- ent pass: one block per tail node ----------------
__global__ __launch_bounds__(EMB) void k_ent(const float* __restrict__ x, const float* __restrict__ r,
                                             const int* __restrict__ tail_off,
                                             const int2* __restrict__ tail_edges,
                                             const int* __restrict__ posmap,
                                             float* __restrict__ xout) {
    int t = blockIdx.x;
    int d = threadIdx.x;        // 0..127
    int k = d >> 4;             // factor
    int sd = d & 15;
    float acc = x[(long)t * EMB + d];   // self-loop contribution (pad rel chunk = 0)
    int beg = tail_off[t], end = tail_off[t + 1];
    for (int e = beg; e < end; ++e) {
        int2 hq = tail_edges[e];
        float v = x[(long)hq.x * EMB + d];
        int pos = posmap[hq.y * KF + k];
        if (pos >= 0) v += r[hq.y * (TN * SDIM) + pos * SDIM + sd];
        acc += v;
    }
    float m = acc / (float)(end - beg + 1);
    xout[(long)t * EMB + d] = m > 0.f ? m : 0.f;
}

// ---------------- rel pass: one block per relation, 4-way edge parallel ----------------
__global__ __launch_bounds__(512) void k_rel(const float* __restrict__ x,
                                             const int* __restrict__ rel_off,
                                             const int2* __restrict__ rel_edges,
                                             const int* __restrict__ topmap,
                                             float* __restrict__ rout) {
    int q = blockIdx.x;
    int g = threadIdx.x >> 7;   // 0..3
    int d = threadIdx.x & 127;
    __shared__ float part[4][EMB];
    float acc = 0.f;
    int beg = rel_off[q], end = rel_off[q + 1];
    for (int e = beg + g; e < end; e += 4) {
        int2 th = rel_edges[e];
        acc += x[(long)th.x * EMB + d] - x[(long)th.y * EMB + d];
    }
    part[g][d] = acc;
    __syncthreads();
    if (g == 0) {
        float s = part[0][d] + part[1][d] + part[2][d] + part[3][d];
        int cnt = end - beg;
        part[0][d] = cnt > 0 ? s / (float)cnt : 0.f;
    }
    __syncthreads();
    if (threadIdx.x < TN * SDIM) {
        int j = threadIdx.x >> 4, sd = threadIdx.x & 15;
        int k = topmap[q * TN + j];
        rout[q * (TN * SDIM) + threadIdx.x] = part[0][k * SDIM + sd];
    }
}

extern "C" void kernel_launch(void* const* d_in, const int* in_sizes, int n_in,
                              void* d_out, int out_size, void* d_ws, size_t ws_size,
                              hipStream_t stream) {
    const float* x0 = (const float*)d_in[0];
    const float* r0 = (const float*)d_in[1];
    const float* rel_att = (const float*)d_in[2];
    const int* edge_index = (const int*)d_in[3];
    const int* edge_type = (const int*)d_in[4];

    const int num_ent = in_sizes[0] / EMB;
    const int num_rel = in_sizes[2] / KF;
    const int nE = in_sizes[4];

    const int* heads = edge_index;
    const int* tails = edge_index + nE;

    // ---- workspace carve-up ----
    char* base = (char*)d_ws;
    size_t off = 0;
    auto carve = [&](size_t bytes) { char* p = base + off; off = (off + bytes + 255) & ~(size_t)255; return p; };
    int* deg        = (int*)carve((size_t)num_ent * 4);
    int* tail_off   = (int*)carve((size_t)(num_ent + 1) * 4);
    int* tail_cur   = (int*)carve((size_t)num_ent * 4);
    int2* tail_edges= (int2*)carve((size_t)nE * 8);
    int* rcnt       = (int*)carve((size_t)num_rel * 4);
    int* rel_off    = (int*)carve((size_t)(num_rel + 1) * 4);
    int* rel_cur    = (int*)carve((size_t)num_rel * 4);
    int2* rel_edges = (int2*)carve((size_t)nE * 8);
    int* posmap     = (int*)carve((size_t)num_rel * KF * 4);
    int* topmap     = (int*)carve((size_t)num_rel * TN * 4);
    float* x1       = (float*)carve((size_t)num_ent * EMB * 4);
    float* r1       = (float*)carve((size_t)num_rel * TN * SDIM * 4);
    (void)ws_size;

    float* x_out = (float*)d_out;                       // num_ent*128
    float* r_out = (float*)d_out + (size_t)num_ent * EMB; // num_rel*64

    // ---- setup (layer-invariant) ----
    hipMemsetAsync(deg, 0, (size_t)num_ent * 4, stream);
    hipMemsetAsync(rcnt, 0, (size_t)num_rel * 4, stream);

    k_relmap<<<(num_rel + 63) / 64, 64, 0, stream>>>(rel_att, num_rel, posmap, topmap);
    k_hist<<<(nE + 255) / 256, 256, 0, stream>>>(tails, edge_type, nE, deg, rcnt);
    k_scan<<<1, 1024, 0, stream>>>(deg, tail_off, num_ent);
    k_scan<<<1, 1024, 0, stream>>>(rcnt, rel_off, num_rel);
    hipMemcpyAsync(tail_cur, tail_off, (size_t)num_ent * 4, hipMemcpyDeviceToDevice, stream);
    hipMemcpyAsync(rel_cur, rel_off, (size_t)num_rel * 4, hipMemcpyDeviceToDevice, stream);
    k_scatter<<<(nE + 255) / 256, 256, 0, stream>>>(heads, tails, edge_type, nE,
                                                    tail_cur, tail_edges, rel_cur, rel_edges);

    // ---- layer 1: x0,r0 -> x1,r1 ----
    k_ent<<<num_ent, EMB, 0, stream>>>(x0, r0, tail_off, tail_edges, posmap, x1);
    k_rel<<<num_rel, 512, 0, stream>>>(x0, rel_off, rel_edges, topmap, r1);

    // ---- layer 2: x1,r1 -> outputs ----
    k_ent<<<num_ent, EMB, 0, stream>>>(x1, r1, tail_off, tail_edges, posmap, x_out);
    k_rel<<<num_rel, 512, 0, stream>>>(x1, rel_off, rel_edges, topmap, r_out);
}

// Round 2
// 915.334 us; speedup vs baseline: 1.0009x; 1.0009x over previous
//
#include <hip/hip_runtime.h>

#define KF 8
#define TN 4
#define SDIM 16
#define EMB 128

// ---------------- per-relation top-k permutation ----------------
__global__ void k_relmap(const float* __restrict__ rel_att, int num_rel,
                         int* __restrict__ posmap, int* __restrict__ topmap) {
    int q = blockIdx.x * blockDim.x + threadIdx.x;
    if (q >= num_rel) return;
    float v[KF]; int idx[KF];
    for (int k = 0; k < KF; ++k) { v[k] = rel_att[q * KF + k]; idx[k] = k; }
    // stable insertion sort, descending (equal keys keep index order == argsort(-att))
    for (int i = 1; i < KF; ++i) {
        float vi = v[i]; int ii = idx[i]; int j = i - 1;
        while (j >= 0 && v[j] < vi) { v[j + 1] = v[j]; idx[j + 1] = idx[j]; --j; }
        v[j + 1] = vi; idx[j + 1] = ii;
    }
    int pos[KF];
    for (int k = 0; k < KF; ++k) pos[k] = -1;
    for (int j = 0; j < TN; ++j) { topmap[q * TN + j] = idx[j]; pos[idx[j]] = j; }
    for (int k = 0; k < KF; ++k) posmap[q * KF + k] = pos[k];
}

// ---------------- histograms ----------------
__global__ void k_hist(const int* __restrict__ tails, const int* __restrict__ types,
                       int nE, int* __restrict__ deg, int* __restrict__ rcnt) {
    int i = blockIdx.x * blockDim.x + threadIdx.x;
    if (i >= nE) return;
    atomicAdd(&deg[tails[i]], 1);
    atomicAdd(&rcnt[types[i]], 1);
}

// ---------------- single-block exclusive scan ----------------
__global__ void k_scan(const int* __restrict__ in, int* __restrict__ out, int n) {
    __shared__ int warp_sums[16];
    int carry = 0;
    int lane = threadIdx.x & 63, wid = threadIdx.x >> 6;
    int nw = blockDim.x >> 6;
    for (int base = 0; base < n; base += blockDim.x) {
        int i = base + (int)threadIdx.x;
        int v = (i < n) ? in[i] : 0;
        int sv = v;
        for (int o = 1; o < 64; o <<= 1) { int t = __shfl_up(sv, o, 64); if (lane >= o) sv += t; }
        if (lane == 63) warp_sums[wid] = sv;
        __syncthreads();
        if (wid == 0 && lane < nw) {
            int ws = warp_sums[lane];
            for (int o = 1; o < 16; o <<= 1) { int t = __shfl_up(ws, o, 64); if (lane >= o) ws += t; }
            warp_sums[lane] = ws;
        }
        __syncthreads();
        int wofs = (wid > 0) ? warp_sums[wid - 1] : 0;
        int total = warp_sums[nw - 1];
        if (i < n) out[i] = carry + wofs + sv - v;
        carry += total;
        __syncthreads();
    }
    if (threadIdx.x == 0) out[n] = carry;
}

// ---------------- CSR scatter ----------------
__global__ void k_scatter(const int* __restrict__ heads, const int* __restrict__ tails,
                          const int* __restrict__ types, int nE,
                          int* __restrict__ tail_cur, int2* __restrict__ tail_edges,
                          int* __restrict__ rel_cur, int2* __restrict__ rel_edges) {
    int i = blockIdx.x * blockDim.x + threadIdx.x;
    if (i >= nE) return;
    int h = heads[i], t = tails[i], q = types[i];
    int p = atomicAdd(&tail_cur[t], 1);
    tail_edges[p] = make_int2(h, q);
    int p2 = atomicAdd(&rel_cur[q], 1);
    rel_edges[p2] = make_int2(t, h);
}

// ---------------- ent pass: one block per tail node ----------------
__global__ __launch_bounds__(EMB) void k_ent(const float* __restrict__ x, const float* __restrict__ r,
                                             const int* __restrict__ tail_off,
                                             const int2* __restrict__ tail_edges,
                                             const int* __restrict__ posmap,
                                             float* __restrict__ xout) {
    int t = blockIdx.x;
    int d = threadIdx.x;        // 0..127
    int k = d >> 4;             // factor
    int sd = d & 15;
    float acc = x[(long)t * EMB + d];   // self-loop contribution (pad rel chunk = 0)
    int beg = tail_off[t], end = tail_off[t + 1];
    for (int e = beg; e < end; ++e) {
        int2 hq = tail_edges[e];
        float v = x[(long)hq.x * EMB + d];
        int pos = posmap[hq.y * KF + k];
        if (pos >= 0) v += r[hq.y * (TN * SDIM) + pos * SDIM + sd];
        acc += v;
    }
    float m = acc / (float)(end - beg + 1);
    xout[(long)t * EMB + d] = m > 0.f ? m : 0.f;
}

// ---------------- rel pass: one block per relation, 4-way edge parallel ----------------
__global__ __launch_bounds__(512) void k_rel(const float* __restrict__ x,
                                             const int* __restrict__ rel_off,
                                             const int2* __restrict__ rel_edges,
                                             const int* __restrict__ topmap,
                                             float* __restrict__ rout) {
    int q = blockIdx.x;
    int g = threadIdx.x >> 7;   // 0..3
    int d = threadIdx.x & 127;
    __shared__ float part[4][EMB];
    float acc = 0.f;
    int beg = rel_off[q], end = rel_off[q + 1];
    for (int e = beg + g; e < end; e += 4) {
        int2 th = rel_edges[e];
        acc += x[(long)th.x * EMB + d] - x[(long)th.y * EMB + d];
    }
    part[g][d] = acc;
    __syncthreads();
    if (g == 0) {
        float s = part[0][d] + part[1][d] + part[2][d] + part[3][d];
        int cnt = end - beg;
        part[0][d] = cnt > 0 ? s / (float)cnt : 0.f;
    }
    __syncthreads();
    if (threadIdx.x < TN * SDIM) {
        int j = threadIdx.x >> 4, sd = threadIdx.x & 15;
        int k = topmap[q * TN + j];
        rout[q * (TN * SDIM) + threadIdx.x] = part[0][k * SDIM + sd];
    }
}

extern "C" void kernel_launch(void* const* d_in, const int* in_sizes, int n_in,
                              void* d_out, int out_size, void* d_ws, size_t ws_size,
                              hipStream_t stream) {
    const float* x0 = (const float*)d_in[0];
    const float* r0 = (const float*)d_in[1];
    const float* rel_att = (const float*)d_in[2];
    const int* edge_index = (const int*)d_in[3];
    const int* edge_type = (const int*)d_in[4];

    const int num_ent = in_sizes[0] / EMB;
    const int num_rel = in_sizes[2] / KF;
    const int nE = in_sizes[4];

    const int* heads = edge_index;
    const int* tails = edge_index + nE;

    // ---- workspace carve-up ----
    char* base = (char*)d_ws;
    size_t off = 0;
    auto carve = [&](size_t bytes) { char* p = base + off; off = (off + bytes + 255) & ~(size_t)255; return p; };
    int* deg        = (int*)carve((size_t)num_ent * 4);
    int* tail_off   = (int*)carve((size_t)(num_ent + 1) * 4);
    int* tail_cur   = (int*)carve((size_t)num_ent * 4);
    int2* tail_edges= (int2*)carve((size_t)nE * 8);
    int* rcnt       = (int*)carve((size_t)num_rel * 4);
    int* rel_off    = (int*)carve((size_t)(num_rel + 1) * 4);
    int* rel_cur    = (int*)carve((size_t)num_rel * 4);
    int2* rel_edges = (int2*)carve((size_t)nE * 8);
    int* posmap     = (int*)carve((size_t)num_rel * KF * 4);
    int* topmap     = (int*)carve((size_t)num_rel * TN * 4);
    float* x1       = (float*)carve((size_t)num_ent * EMB * 4);
    float* r1       = (float*)carve((size_t)num_rel * TN * SDIM * 4);
    (void)ws_size;

    float* x_out = (float*)d_out;                       // num_ent*128
    float* r_out = (float*)d_out + (size_t)num_ent * EMB; // num_rel*64

    // ---- setup (layer-invariant) ----
    hipMemsetAsync(deg, 0, (size_t)num_ent * 4, stream);
    hipMemsetAsync(rcnt, 0, (size_t)num_rel * 4, stream);

    k_relmap<<<(num_rel + 63) / 64, 64, 0, stream>>>(rel_att, num_rel, posmap, topmap);
    k_hist<<<(nE + 255) / 256, 256, 0, stream>>>(tails, edge_type, nE, deg, rcnt);
    k_scan<<<1, 1024, 0, stream>>>(deg, tail_off, num_ent);
    k_scan<<<1, 1024, 0, stream>>>(rcnt, rel_off, num_rel);
    hipMemcpyAsync(tail_cur, tail_off, (size_t)num_ent * 4, hipMemcpyDeviceToDevice, stream);
    hipMemcpyAsync(rel_cur, rel_off, (size_t)num_rel * 4, hipMemcpyDeviceToDevice, stream);
    k_scatter<<<(nE + 255) / 256, 256, 0, stream>>>(heads, tails, edge_type, nE,
                                                    tail_cur, tail_edges, rel_cur, rel_edges);

    // ---- layer 1: x0,r0 -> x1,r1 ----
    k_ent<<<num_ent, EMB, 0, stream>>>(x0, r0, tail_off, tail_edges, posmap, x1);
    k_rel<<<num_rel, 512, 0, stream>>>(x0, rel_off, rel_edges, topmap, r1);

    // ---- layer 2: x1,r1 -> outputs ----
    k_ent<<<num_ent, EMB, 0, stream>>>(x1, r1, tail_off, tail_edges, posmap, x_out);
    k_rel<<<num_rel, 512, 0, stream>>>(x1, rel_off, rel_edges, topmap, r_out);
}

// Round 3
// 639.936 us; speedup vs baseline: 1.4317x; 1.4304x over previous
//
#include <hip/hip_runtime.h>

#define KF 8
#define TN 4
#define SDIM 16
#define EMB 128
#define NS 8   // rel-pass split factor

typedef unsigned int u32;

// ---------------- per-relation top-k permutation ----------------
__global__ void k_relmap(const float* __restrict__ rel_att, int num_rel,
                         int* __restrict__ posmap, int* __restrict__ topmap) {
    int q = blockIdx.x * blockDim.x + threadIdx.x;
    if (q >= num_rel) return;
    float v[KF]; int idx[KF];
    for (int k = 0; k < KF; ++k) { v[k] = rel_att[q * KF + k]; idx[k] = k; }
    // stable insertion sort, descending (ties keep index order == argsort(-att))
    for (int i = 1; i < KF; ++i) {
        float vi = v[i]; int ii = idx[i]; int j = i - 1;
        while (j >= 0 && v[j] < vi) { v[j + 1] = v[j]; idx[j + 1] = idx[j]; --j; }
        v[j + 1] = vi; idx[j + 1] = ii;
    }
    int pos[KF];
    for (int k = 0; k < KF; ++k) pos[k] = -1;
    for (int j = 0; j < TN; ++j) { topmap[q * TN + j] = idx[j]; pos[idx[j]] = j; }
    for (int k = 0; k < KF; ++k) posmap[q * KF + k] = pos[k];
}

// ---------------- histograms ----------------
__global__ void k_hist(const int* __restrict__ tails, const int* __restrict__ types,
                       int nE, int* __restrict__ deg, int* __restrict__ rcnt) {
    int i = blockIdx.x * blockDim.x + threadIdx.x;
    if (i >= nE) return;
    atomicAdd(&deg[tails[i]], 1);
    atomicAdd(&rcnt[types[i]], 1);
}

// ---------------- single-block exclusive scan ----------------
__global__ void k_scan(const int* __restrict__ in, int* __restrict__ out, int n) {
    __shared__ int warp_sums[16];
    int carry = 0;
    int lane = threadIdx.x & 63, wid = threadIdx.x >> 6;
    int nw = blockDim.x >> 6;
    for (int base = 0; base < n; base += blockDim.x) {
        int i = base + (int)threadIdx.x;
        int v = (i < n) ? in[i] : 0;
        int sv = v;
        for (int o = 1; o < 64; o <<= 1) { int t = __shfl_up(sv, o, 64); if (lane >= o) sv += t; }
        if (lane == 63) warp_sums[wid] = sv;
        __syncthreads();
        if (wid == 0 && lane < nw) {
            int ws = warp_sums[lane];
            for (int o = 1; o < 16; o <<= 1) { int t = __shfl_up(ws, o, 64); if (lane >= o) ws += t; }
            warp_sums[lane] = ws;
        }
        __syncthreads();
        int wofs = (wid > 0) ? warp_sums[wid - 1] : 0;
        int total = warp_sums[nw - 1];
        if (i < n) out[i] = carry + wofs + sv - v;
        carry += total;
        __syncthreads();
    }
    if (threadIdx.x == 0) out[n] = carry;
}

// ---------------- CSR scatter (packed 4B payloads) ----------------
__global__ void k_scatter(const int* __restrict__ heads, const int* __restrict__ tails,
                          const int* __restrict__ types, int nE,
                          int* __restrict__ tail_cur, u32* __restrict__ tail_edges,
                          int* __restrict__ rel_cur, u32* __restrict__ rel_edges) {
    int i = blockIdx.x * blockDim.x + threadIdx.x;
    if (i >= nE) return;
    u32 h = (u32)heads[i], t = (u32)tails[i], q = (u32)types[i];
    int p = atomicAdd(&tail_cur[t], 1);
    tail_edges[p] = h | (q << 16);        // h < 65536, q <= 500
    int p2 = atomicAdd(&rel_cur[q], 1);
    rel_edges[p2] = t | (h << 16);        // t,h < 65536
}

// ---------------- ent pass: one 64-thread block per tail, float4, 2 edges/iter ----------------
__global__ __launch_bounds__(64) void k_ent(const float4* __restrict__ x4, const float4* __restrict__ r4,
                                            const int* __restrict__ tail_off,
                                            const u32* __restrict__ tail_edges,
                                            const int* __restrict__ posmap,
                                            float4* __restrict__ xout) {
    int t = blockIdx.x;
    int lane = threadIdx.x;
    int sub = lane >> 5, c = lane & 31;       // c indexes float4 within the 128-dim row
    int beg = tail_off[t], end = tail_off[t + 1];
    float4 acc = make_float4(0.f, 0.f, 0.f, 0.f);
    for (int e = beg + sub; e < end; e += 2) {
        u32 w = tail_edges[e];
        int h = (int)(w & 0xFFFFu);
        int q = (int)(w >> 16);
        float4 v = x4[(size_t)h * 32 + c];
        int pos = posmap[q * KF + (c >> 2)];  // factor k = c>>2
        if (pos >= 0) {
            float4 rv = r4[q * 16 + pos * 4 + (c & 3)];
            v.x += rv.x; v.y += rv.y; v.z += rv.z; v.w += rv.w;
        }
        acc.x += v.x; acc.y += v.y; acc.z += v.z; acc.w += v.w;
    }
    acc.x += __shfl_xor(acc.x, 32, 64);
    acc.y += __shfl_xor(acc.y, 32, 64);
    acc.z += __shfl_xor(acc.z, 32, 64);
    acc.w += __shfl_xor(acc.w, 32, 64);
    if (sub == 0) {
        float4 s = x4[(size_t)t * 32 + c];    // self-loop contribution
        float inv = 1.f / (float)(end - beg + 1);
        float4 o;
        o.x = (acc.x + s.x) * inv; o.x = o.x > 0.f ? o.x : 0.f;
        o.y = (acc.y + s.y) * inv; o.y = o.y > 0.f ? o.y : 0.f;
        o.z = (acc.z + s.z) * inv; o.z = o.z > 0.f ? o.z : 0.f;
        o.w = (acc.w + s.w) * inv; o.w = o.w > 0.f ? o.w : 0.f;
        xout[(size_t)t * 32 + c] = o;
    }
}

// ---------------- rel pass: grid (num_rel, NS), 256 threads, partial sums + atomic merge ----------------
__global__ __launch_bounds__(256) void k_rel(const float4* __restrict__ x4,
                                             const int* __restrict__ rel_off,
                                             const u32* __restrict__ rel_edges,
                                             float* __restrict__ rsum) {
    int q = blockIdx.x;
    int s = blockIdx.y;
    int tid = threadIdx.x;
    int wid = tid >> 6, lane = tid & 63;
    int sub = lane >> 5, c = lane & 31;
    int beg = rel_off[q], end = rel_off[q + 1];
    int stride = (int)gridDim.y * 8;          // NS * (4 waves * 2 edges)
    float4 acc = make_float4(0.f, 0.f, 0.f, 0.f);
    for (int e = beg + s * 8 + wid * 2 + sub; e < end; e += stride) {
        u32 w = rel_edges[e];
        int t = (int)(w & 0xFFFFu);
        int h = (int)(w >> 16);
        float4 a = x4[(size_t)t * 32 + c];
        float4 b = x4[(size_t)h * 32 + c];
        acc.x += a.x - b.x; acc.y += a.y - b.y; acc.z += a.z - b.z; acc.w += a.w - b.w;
    }
    acc.x += __shfl_xor(acc.x, 32, 64);
    acc.y += __shfl_xor(acc.y, 32, 64);
    acc.z += __shfl_xor(acc.z, 32, 64);
    acc.w += __shfl_xor(acc.w, 32, 64);
    __shared__ float4 part[4][32];
    if (sub == 0) part[wid][c] = acc;
    __syncthreads();
    if (tid < EMB) {
        const float* pf = (const float*)part;
        float v = pf[0 * EMB + tid] + pf[1 * EMB + tid] + pf[2 * EMB + tid] + pf[3 * EMB + tid];
        atomicAdd(&rsum[(size_t)q * EMB + tid], v);
    }
}

// ---------------- rel finalize: mean + top-4 gather ----------------
__global__ __launch_bounds__(64) void k_relfin(const float* __restrict__ rsum,
                                               const int* __restrict__ rel_off,
                                               const int* __restrict__ topmap,
                                               float* __restrict__ rout) {
    int q = blockIdx.x;
    int t = threadIdx.x;                      // 0..63
    int cnt = rel_off[q + 1] - rel_off[q];
    int j = t >> 4, sd = t & 15;
    int k = topmap[q * TN + j];
    float v = cnt > 0 ? rsum[(size_t)q * EMB + k * SDIM + sd] / (float)cnt : 0.f;
    rout[q * (TN * SDIM) + t] = v;
}

extern "C" void kernel_launch(void* const* d_in, const int* in_sizes, int n_in,
                              void* d_out, int out_size, void* d_ws, size_t ws_size,
                              hipStream_t stream) {
    const float* x0 = (const float*)d_in[0];
    const float* r0 = (const float*)d_in[1];
    const float* rel_att = (const float*)d_in[2];
    const int* edge_index = (const int*)d_in[3];
    const int* edge_type = (const int*)d_in[4];

    const int num_ent = in_sizes[0] / EMB;
    const int num_rel = in_sizes[2] / KF;
    const int nE = in_sizes[4];

    const int* heads = edge_index;
    const int* tails = edge_index + nE;

    // ---- workspace carve-up ----
    char* base = (char*)d_ws;
    size_t off = 0;
    auto carve = [&](size_t bytes) { char* p = base + off; off = (off + bytes + 255) & ~(size_t)255; return p; };
    int* deg        = (int*)carve((size_t)num_ent * 4);
    int* tail_off   = (int*)carve((size_t)(num_ent + 1) * 4);
    int* tail_cur   = (int*)carve((size_t)num_ent * 4);
    u32* tail_edges = (u32*)carve((size_t)nE * 4);
    int* rcnt       = (int*)carve((size_t)num_rel * 4);
    int* rel_off    = (int*)carve((size_t)(num_rel + 1) * 4);
    int* rel_cur    = (int*)carve((size_t)num_rel * 4);
    u32* rel_edges  = (u32*)carve((size_t)nE * 4);
    int* posmap     = (int*)carve((size_t)num_rel * KF * 4);
    int* topmap     = (int*)carve((size_t)num_rel * TN * 4);
    float* x1       = (float*)carve((size_t)num_ent * EMB * 4);
    float* r1       = (float*)carve((size_t)num_rel * TN * SDIM * 4);
    float* rsumA    = (float*)carve((size_t)num_rel * EMB * 4);
    float* rsumB    = (float*)carve((size_t)num_rel * EMB * 4);
    (void)ws_size;

    float* x_out = (float*)d_out;                         // num_ent*128
    float* r_out = (float*)d_out + (size_t)num_ent * EMB; // num_rel*64

    // ---- setup (layer-invariant) ----
    hipMemsetAsync(deg, 0, (size_t)num_ent * 4, stream);
    hipMemsetAsync(rcnt, 0, (size_t)num_rel * 4, stream);
    hipMemsetAsync(rsumA, 0, (size_t)num_rel * EMB * 4, stream);
    hipMemsetAsync(rsumB, 0, (size_t)num_rel * EMB * 4, stream);

    k_relmap<<<(num_rel + 63) / 64, 64, 0, stream>>>(rel_att, num_rel, posmap, topmap);
    k_hist<<<(nE + 255) / 256, 256, 0, stream>>>(tails, edge_type, nE, deg, rcnt);
    k_scan<<<1, 1024, 0, stream>>>(deg, tail_off, num_ent);
    k_scan<<<1, 1024, 0, stream>>>(rcnt, rel_off, num_rel);
    hipMemcpyAsync(tail_cur, tail_off, (size_t)num_ent * 4, hipMemcpyDeviceToDevice, stream);
    hipMemcpyAsync(rel_cur, rel_off, (size_t)num_rel * 4, hipMemcpyDeviceToDevice, stream);
    k_scatter<<<(nE + 255) / 256, 256, 0, stream>>>(heads, tails, edge_type, nE,
                                                    tail_cur, tail_edges, rel_cur, rel_edges);

    dim3 relgrid(num_rel, NS);

    // ---- layer 1: x0,r0 -> x1,r1 ----
    k_ent<<<num_ent, 64, 0, stream>>>((const float4*)x0, (const float4*)r0, tail_off, tail_edges, posmap, (float4*)x1);
    k_rel<<<relgrid, 256, 0, stream>>>((const float4*)x0, rel_off, rel_edges, rsumA);
    k_relfin<<<num_rel, 64, 0, stream>>>(rsumA, rel_off, topmap, r1);

    // ---- layer 2: x1,r1 -> outputs ----
    k_ent<<<num_ent, 64, 0, stream>>>((const float4*)x1, (const float4*)r1, tail_off, tail_edges, posmap, (float4*)x_out);
    k_rel<<<relgrid, 256, 0, stream>>>((const float4*)x1, rel_off, rel_edges, rsumB);
    k_relfin<<<num_rel, 64, 0, stream>>>(rsumB, rel_off, topmap, r_out);
}

// Round 4
// 362.489 us; speedup vs baseline: 2.5275x; 1.7654x over previous
//
#include <hip/hip_runtime.h>

#define KF 8
#define TN 4
#define SDIM 16
#define EMB 128
#define NS 8     // rel-pass split factor
#define NB 128   // rel-scatter chunk count
#define NRMAX 512

typedef unsigned int u32;

// ---------------- per-relation top-k permutation ----------------
__global__ void k_relmap(const float* __restrict__ rel_att, int num_rel,
                         int* __restrict__ posmap, int* __restrict__ topmap) {
    int q = blockIdx.x * blockDim.x + threadIdx.x;
    if (q >= num_rel) return;
    float v[KF]; int idx[KF];
    for (int k = 0; k < KF; ++k) { v[k] = rel_att[q * KF + k]; idx[k] = k; }
    for (int i = 1; i < KF; ++i) {
        float vi = v[i]; int ii = idx[i]; int j = i - 1;
        while (j >= 0 && v[j] < vi) { v[j + 1] = v[j]; idx[j + 1] = idx[j]; --j; }
        v[j + 1] = vi; idx[j + 1] = ii;
    }
    int pos[KF];
    for (int k = 0; k < KF; ++k) pos[k] = -1;
    for (int j = 0; j < TN; ++j) { topmap[q * TN + j] = idx[j]; pos[idx[j]] = j; }
    for (int k = 0; k < KF; ++k) posmap[q * KF + k] = pos[k];
}

// ---------------- histograms: deg (global, shallow) + rcnt (LDS, flushed per block) ----------------
__global__ __launch_bounds__(256) void k_hist(const int* __restrict__ tails, const int* __restrict__ types,
                                              int nE, int num_rel,
                                              int* __restrict__ deg, int* __restrict__ rcnt) {
    __shared__ int hist[NRMAX];
    for (int q = threadIdx.x; q < num_rel; q += 256) hist[q] = 0;
    __syncthreads();
    for (int i = blockIdx.x * 256 + threadIdx.x; i < nE; i += gridDim.x * 256) {
        atomicAdd(&deg[tails[i]], 1);
        atomicAdd(&hist[types[i]], 1);
    }
    __syncthreads();
    for (int q = threadIdx.x; q < num_rel; q += 256) {
        int h = hist[q];
        if (h) atomicAdd(&rcnt[q], h);
    }
}

// ---------------- single-block exclusive scan ----------------
__global__ void k_scan(const int* __restrict__ in, int* __restrict__ out, int n) {
    __shared__ int warp_sums[16];
    int carry = 0;
    int lane = threadIdx.x & 63, wid = threadIdx.x >> 6;
    int nw = blockDim.x >> 6;
    for (int base = 0; base < n; base += blockDim.x) {
        int i = base + (int)threadIdx.x;
        int v = (i < n) ? in[i] : 0;
        int sv = v;
        for (int o = 1; o < 64; o <<= 1) { int t = __shfl_up(sv, o, 64); if (lane >= o) sv += t; }
        if (lane == 63) warp_sums[wid] = sv;
        __syncthreads();
        if (wid == 0 && lane < nw) {
            int ws = warp_sums[lane];
            for (int o = 1; o < 16; o <<= 1) { int t = __shfl_up(ws, o, 64); if (lane >= o) ws += t; }
            warp_sums[lane] = ws;
        }
        __syncthreads();
        int wofs = (wid > 0) ? warp_sums[wid - 1] : 0;
        int total = warp_sums[nw - 1];
        if (i < n) out[i] = carry + wofs + sv - v;
        carry += total;
        __syncthreads();
    }
    if (threadIdx.x == 0) out[n] = carry;
}

// ---------------- tail CSR scatter: XCD-partitioned by tail range ----------------
__global__ __launch_bounds__(256) void k_scatter_tail(const int* __restrict__ heads,
                                                      const int* __restrict__ tails,
                                                      const int* __restrict__ types,
                                                      int nE, int num_ent,
                                                      int* __restrict__ tail_cur,
                                                      u32* __restrict__ tail_edges) {
    int bi = blockIdx.x;
    int xcd = bi & 7;            // HW maps blockIdx round-robin across 8 XCDs
    int w = bi >> 3;
    int nw = gridDim.x >> 3;
    int per = (num_ent + 7) >> 3;
    int lo = xcd * per, hi = min(lo + per, num_ent);
    for (int i = w * 256 + (int)threadIdx.x; i < nE; i += nw * 256) {
        int t = tails[i];
        if (t >= lo && t < hi) {
            int p = atomicAdd(&tail_cur[t], 1);   // depth ~deg(t) ~ 10
            tail_edges[p] = (u32)heads[i] | ((u32)types[i] << 16);
        }
    }
}

// ---------------- rel CSR scatter: LDS hist -> block-granular reservation -> LDS ranks ----------------
__global__ __launch_bounds__(256) void k_scatter_rel(const int* __restrict__ heads,
                                                     const int* __restrict__ tails,
                                                     const int* __restrict__ types,
                                                     int nE, int num_rel,
                                                     int* __restrict__ rel_cur,
                                                     u32* __restrict__ rel_edges) {
    __shared__ int hist[NRMAX];
    __shared__ int base[NRMAX];
    int bi = blockIdx.x;                         // 0..NB-1
    int c = (bi & 7) * (NB >> 3) + (bi >> 3);    // XCD-contiguous chunk mapping
    int chunk = (nE + NB - 1) / NB;
    int beg = c * chunk, end = min(beg + chunk, nE);
    for (int q = threadIdx.x; q < num_rel; q += 256) hist[q] = 0;
    __syncthreads();
    for (int i = beg + (int)threadIdx.x; i < end; i += 256) atomicAdd(&hist[types[i]], 1);
    __syncthreads();
    for (int q = threadIdx.x; q < num_rel; q += 256) {
        int h = hist[q];
        base[q] = h > 0 ? atomicAdd(&rel_cur[q], h) : 0;   // depth NB=128, block-granular
        hist[q] = 0;
    }
    __syncthreads();
    for (int i = beg + (int)threadIdx.x; i < end; i += 256) {
        int q = types[i];
        int rank = atomicAdd(&hist[q], 1);       // fast LDS atomic
        rel_edges[base[q] + rank] = (u32)tails[i] | ((u32)heads[i] << 16);
    }
}

// ---------------- ent pass: one 64-thread block per tail, float4, 2 edges/iter ----------------
__global__ __launch_bounds__(64) void k_ent(const float4* __restrict__ x4, const float4* __restrict__ r4,
                                            const int* __restrict__ tail_off,
                                            const u32* __restrict__ tail_edges,
                                            const int* __restrict__ posmap,
                                            float4* __restrict__ xout) {
    int t = blockIdx.x;
    int lane = threadIdx.x;
    int sub = lane >> 5, c = lane & 31;
    int beg = tail_off[t], end = tail_off[t + 1];
    float4 acc = make_float4(0.f, 0.f, 0.f, 0.f);
    for (int e = beg + sub; e < end; e += 2) {
        u32 w = tail_edges[e];
        int h = (int)(w & 0xFFFFu);
        int q = (int)(w >> 16);
        float4 v = x4[(size_t)h * 32 + c];
        int pos = posmap[q * KF + (c >> 2)];
        if (pos >= 0) {
            float4 rv = r4[q * 16 + pos * 4 + (c & 3)];
            v.x += rv.x; v.y += rv.y; v.z += rv.z; v.w += rv.w;
        }
        acc.x += v.x; acc.y += v.y; acc.z += v.z; acc.w += v.w;
    }
    acc.x += __shfl_xor(acc.x, 32, 64);
    acc.y += __shfl_xor(acc.y, 32, 64);
    acc.z += __shfl_xor(acc.z, 32, 64);
    acc.w += __shfl_xor(acc.w, 32, 64);
    if (sub == 0) {
        float4 s = x4[(size_t)t * 32 + c];
        float inv = 1.f / (float)(end - beg + 1);
        float4 o;
        o.x = (acc.x + s.x) * inv; o.x = o.x > 0.f ? o.x : 0.f;
        o.y = (acc.y + s.y) * inv; o.y = o.y > 0.f ? o.y : 0.f;
        o.z = (acc.z + s.z) * inv; o.z = o.z > 0.f ? o.z : 0.f;
        o.w = (acc.w + s.w) * inv; o.w = o.w > 0.f ? o.w : 0.f;
        xout[(size_t)t * 32 + c] = o;
    }
}

// ---------------- rel pass: grid (num_rel, NS), 256 threads, partial sums + atomic merge ----------------
__global__ __launch_bounds__(256) void k_rel(const float4* __restrict__ x4,
                                             const int* __restrict__ rel_off,
                                             const u32* __restrict__ rel_edges,
                                             float* __restrict__ rsum) {
    int q = blockIdx.x;
    int s = blockIdx.y;
    int tid = threadIdx.x;
    int wid = tid >> 6, lane = tid & 63;
    int sub = lane >> 5, c = lane & 31;
    int beg = rel_off[q], end = rel_off[q + 1];
    int stride = (int)gridDim.y * 8;
    float4 acc = make_float4(0.f, 0.f, 0.f, 0.f);
    for (int e = beg + s * 8 + wid * 2 + sub; e < end; e += stride) {
        u32 w = rel_edges[e];
        int t = (int)(w & 0xFFFFu);
        int h = (int)(w >> 16);
        float4 a = x4[(size_t)t * 32 + c];
        float4 b = x4[(size_t)h * 32 + c];
        acc.x += a.x - b.x; acc.y += a.y - b.y; acc.z += a.z - b.z; acc.w += a.w - b.w;
    }
    acc.x += __shfl_xor(acc.x, 32, 64);
    acc.y += __shfl_xor(acc.y, 32, 64);
    acc.z += __shfl_xor(acc.z, 32, 64);
    acc.w += __shfl_xor(acc.w, 32, 64);
    __shared__ float4 part[4][32];
    if (sub == 0) part[wid][c] = acc;
    __syncthreads();
    if (tid < EMB) {
        const float* pf = (const float*)part;
        float v = pf[0 * EMB + tid] + pf[1 * EMB + tid] + pf[2 * EMB + tid] + pf[3 * EMB + tid];
        atomicAdd(&rsum[(size_t)q * EMB + tid], v);
    }
}

// ---------------- rel finalize: mean + top-4 gather ----------------
__global__ __launch_bounds__(64) void k_relfin(const float* __restrict__ rsum,
                                               const int* __restrict__ rel_off,
                                               const int* __restrict__ topmap,
                                               float* __restrict__ rout) {
    int q = blockIdx.x;
    int t = threadIdx.x;
    int cnt = rel_off[q + 1] - rel_off[q];
    int j = t >> 4, sd = t & 15;
    int k = topmap[q * TN + j];
    float v = cnt > 0 ? rsum[(size_t)q * EMB + k * SDIM + sd] / (float)cnt : 0.f;
    rout[q * (TN * SDIM) + t] = v;
}

extern "C" void kernel_launch(void* const* d_in, const int* in_sizes, int n_in,
                              void* d_out, int out_size, void* d_ws, size_t ws_size,
                              hipStream_t stream) {
    const float* x0 = (const float*)d_in[0];
    const float* r0 = (const float*)d_in[1];
    const float* rel_att = (const float*)d_in[2];
    const int* edge_index = (const int*)d_in[3];
    const int* edge_type = (const int*)d_in[4];

    const int num_ent = in_sizes[0] / EMB;
    const int num_rel = in_sizes[2] / KF;
    const int nE = in_sizes[4];

    const int* heads = edge_index;
    const int* tails = edge_index + nE;

    // ---- workspace carve-up ----
    char* base = (char*)d_ws;
    size_t off = 0;
    auto carve = [&](size_t bytes) { char* p = base + off; off = (off + bytes + 255) & ~(size_t)255; return p; };
    int* deg        = (int*)carve((size_t)num_ent * 4);
    int* tail_off   = (int*)carve((size_t)(num_ent + 1) * 4);
    int* tail_cur   = (int*)carve((size_t)num_ent * 4);
    u32* tail_edges = (u32*)carve((size_t)nE * 4);
    int* rcnt       = (int*)carve((size_t)num_rel * 4);
    int* rel_off    = (int*)carve((size_t)(num_rel + 1) * 4);
    int* rel_cur    = (int*)carve((size_t)num_rel * 4);
    u32* rel_edges  = (u32*)carve((size_t)nE * 4);
    int* posmap     = (int*)carve((size_t)num_rel * KF * 4);
    int* topmap     = (int*)carve((size_t)num_rel * TN * 4);
    float* x1       = (float*)carve((size_t)num_ent * EMB * 4);
    float* r1       = (float*)carve((size_t)num_rel * TN * SDIM * 4);
    float* rsumA    = (float*)carve((size_t)num_rel * EMB * 4);
    float* rsumB    = (float*)carve((size_t)num_rel * EMB * 4);
    (void)ws_size;

    float* x_out = (float*)d_out;
    float* r_out = (float*)d_out + (size_t)num_ent * EMB;

    // ---- setup (layer-invariant) ----
    hipMemsetAsync(deg, 0, (size_t)num_ent * 4, stream);
    hipMemsetAsync(rcnt, 0, (size_t)num_rel * 4, stream);
    hipMemsetAsync(rsumA, 0, (size_t)num_rel * EMB * 4, stream);
    hipMemsetAsync(rsumB, 0, (size_t)num_rel * EMB * 4, stream);

    k_relmap<<<(num_rel + 63) / 64, 64, 0, stream>>>(rel_att, num_rel, posmap, topmap);
    k_hist<<<128, 256, 0, stream>>>(tails, edge_type, nE, num_rel, deg, rcnt);
    k_scan<<<1, 1024, 0, stream>>>(deg, tail_off, num_ent);
    k_scan<<<1, 1024, 0, stream>>>(rcnt, rel_off, num_rel);
    hipMemcpyAsync(tail_cur, tail_off, (size_t)num_ent * 4, hipMemcpyDeviceToDevice, stream);
    hipMemcpyAsync(rel_cur, rel_off, (size_t)num_rel * 4, hipMemcpyDeviceToDevice, stream);
    k_scatter_tail<<<512, 256, 0, stream>>>(heads, tails, edge_type, nE, num_ent, tail_cur, tail_edges);
    k_scatter_rel<<<NB, 256, 0, stream>>>(heads, tails, edge_type, nE, num_rel, rel_cur, rel_edges);

    dim3 relgrid(num_rel, NS);

    // ---- layer 1: x0,r0 -> x1,r1 ----
    k_ent<<<num_ent, 64, 0, stream>>>((const float4*)x0, (const float4*)r0, tail_off, tail_edges, posmap, (float4*)x1);
    k_rel<<<relgrid, 256, 0, stream>>>((const float4*)x0, rel_off, rel_edges, rsumA);
    k_relfin<<<num_rel, 64, 0, stream>>>(rsumA, rel_off, topmap, r1);

    // ---- layer 2: x1,r1 -> outputs ----
    k_ent<<<num_ent, 64, 0, stream>>>((const float4*)x1, (const float4*)r1, tail_off, tail_edges, posmap, (float4*)x_out);
    k_rel<<<relgrid, 256, 0, stream>>>((const float4*)x1, rel_off, rel_edges, rsumB);
    k_relfin<<<num_rel, 64, 0, stream>>>(rsumB, rel_off, topmap, r_out);
}

// Round 5
// 322.615 us; speedup vs baseline: 2.8399x; 1.1236x over previous
//
#include <hip/hip_runtime.h>

#define KF 8
#define TN 4
#define SDIM 16
#define EMB 128
#define NS 8     // rel-pass split factor
#define NB 128   // rel-scatter chunk count
#define NRMAX 512

typedef unsigned int u32;

// ---- bf16 helpers (manual RNE pack, bit-shift unpack) ----
__device__ __forceinline__ u32 pack2bf(float a, float b) {
    u32 ua = __float_as_uint(a), ub = __float_as_uint(b);
    ua = (ua + 0x7FFFu + ((ua >> 16) & 1u)) >> 16;
    ub = (ub + 0x7FFFu + ((ub >> 16) & 1u)) >> 16;
    return ua | (ub << 16);
}
__device__ __forceinline__ float lo16(u32 w) { return __uint_as_float(w << 16); }
__device__ __forceinline__ float hi16(u32 w) { return __uint_as_float(w & 0xFFFF0000u); }

// ---------------- fp32 -> bf16 row mirror ----------------
__global__ __launch_bounds__(256) void k_tobf16(const float4* __restrict__ x4, u32* __restrict__ xh, int n4) {
    int i = blockIdx.x * 256 + threadIdx.x;
    if (i >= n4) return;
    float4 v = x4[i];
    ((uint2*)xh)[i] = make_uint2(pack2bf(v.x, v.y), pack2bf(v.z, v.w));
}

// ---------------- per-relation top-k permutation ----------------
__global__ void k_relmap(const float* __restrict__ rel_att, int num_rel,
                         int* __restrict__ posmap, int* __restrict__ topmap) {
    int q = blockIdx.x * blockDim.x + threadIdx.x;
    if (q >= num_rel) return;
    float v[KF]; int idx[KF];
    for (int k = 0; k < KF; ++k) { v[k] = rel_att[q * KF + k]; idx[k] = k; }
    for (int i = 1; i < KF; ++i) {
        float vi = v[i]; int ii = idx[i]; int j = i - 1;
        while (j >= 0 && v[j] < vi) { v[j + 1] = v[j]; idx[j + 1] = idx[j]; --j; }
        v[j + 1] = vi; idx[j + 1] = ii;
    }
    int pos[KF];
    for (int k = 0; k < KF; ++k) pos[k] = -1;
    for (int j = 0; j < TN; ++j) { topmap[q * TN + j] = idx[j]; pos[idx[j]] = j; }
    for (int k = 0; k < KF; ++k) posmap[q * KF + k] = pos[k];
}

// ---------------- histograms ----------------
__global__ __launch_bounds__(256) void k_hist(const int* __restrict__ tails, const int* __restrict__ types,
                                              int nE, int num_rel,
                                              int* __restrict__ deg, int* __restrict__ rcnt) {
    __shared__ int hist[NRMAX];
    for (int q = threadIdx.x; q < num_rel; q += 256) hist[q] = 0;
    __syncthreads();
    for (int i = blockIdx.x * 256 + threadIdx.x; i < nE; i += gridDim.x * 256) {
        atomicAdd(&deg[tails[i]], 1);
        atomicAdd(&hist[types[i]], 1);
    }
    __syncthreads();
    for (int q = threadIdx.x; q < num_rel; q += 256) {
        int h = hist[q];
        if (h) atomicAdd(&rcnt[q], h);
    }
}

// ---------------- single-block exclusive scan ----------------
__global__ void k_scan(const int* __restrict__ in, int* __restrict__ out, int n) {
    __shared__ int warp_sums[16];
    int carry = 0;
    int lane = threadIdx.x & 63, wid = threadIdx.x >> 6;
    int nw = blockDim.x >> 6;
    for (int base = 0; base < n; base += blockDim.x) {
        int i = base + (int)threadIdx.x;
        int v = (i < n) ? in[i] : 0;
        int sv = v;
        for (int o = 1; o < 64; o <<= 1) { int t = __shfl_up(sv, o, 64); if (lane >= o) sv += t; }
        if (lane == 63) warp_sums[wid] = sv;
        __syncthreads();
        if (wid == 0 && lane < nw) {
            int ws = warp_sums[lane];
            for (int o = 1; o < 16; o <<= 1) { int t = __shfl_up(ws, o, 64); if (lane >= o) ws += t; }
            warp_sums[lane] = ws;
        }
        __syncthreads();
        int wofs = (wid > 0) ? warp_sums[wid - 1] : 0;
        int total = warp_sums[nw - 1];
        if (i < n) out[i] = carry + wofs + sv - v;
        carry += total;
        __syncthreads();
    }
    if (threadIdx.x == 0) out[n] = carry;
}

// ---------------- tail CSR scatter: XCD-partitioned by tail range ----------------
__global__ __launch_bounds__(256) void k_scatter_tail(const int* __restrict__ heads,
                                                      const int* __restrict__ tails,
                                                      const int* __restrict__ types,
                                                      int nE, int num_ent,
                                                      int* __restrict__ tail_cur,
                                                      u32* __restrict__ tail_edges) {
    int bi = blockIdx.x;
    int xcd = bi & 7;
    int w = bi >> 3;
    int nw = gridDim.x >> 3;
    int per = (num_ent + 7) >> 3;
    int lo = xcd * per, hi = min(lo + per, num_ent);
    for (int i = w * 256 + (int)threadIdx.x; i < nE; i += nw * 256) {
        int t = tails[i];
        if (t >= lo && t < hi) {
            int p = atomicAdd(&tail_cur[t], 1);
            tail_edges[p] = (u32)heads[i] | ((u32)types[i] << 16);
        }
    }
}

// ---------------- rel CSR scatter: LDS hist -> block-granular reservation -> LDS ranks ----------------
__global__ __launch_bounds__(256) void k_scatter_rel(const int* __restrict__ heads,
                                                     const int* __restrict__ tails,
                                                     const int* __restrict__ types,
                                                     int nE, int num_rel,
                                                     int* __restrict__ rel_cur,
                                                     u32* __restrict__ rel_edges) {
    __shared__ int hist[NRMAX];
    __shared__ int base[NRMAX];
    int bi = blockIdx.x;
    int c = (bi & 7) * (NB >> 3) + (bi >> 3);
    int chunk = (nE + NB - 1) / NB;
    int beg = c * chunk, end = min(beg + chunk, nE);
    for (int q = threadIdx.x; q < num_rel; q += 256) hist[q] = 0;
    __syncthreads();
    for (int i = beg + (int)threadIdx.x; i < end; i += 256) atomicAdd(&hist[types[i]], 1);
    __syncthreads();
    for (int q = threadIdx.x; q < num_rel; q += 256) {
        int h = hist[q];
        base[q] = h > 0 ? atomicAdd(&rel_cur[q], h) : 0;
        hist[q] = 0;
    }
    __syncthreads();
    for (int i = beg + (int)threadIdx.x; i < end; i += 256) {
        int q = types[i];
        int rank = atomicAdd(&hist[q], 1);
        rel_edges[base[q] + rank] = (u32)tails[i] | ((u32)heads[i] << 16);
    }
}

// ---------------- ent pass: bf16 gathers, 4 tails per 256-thread block ----------------
template <bool OUT_BF16>
__global__ __launch_bounds__(256) void k_ent(const u32* __restrict__ xh, const float4* __restrict__ r4,
                                             const int* __restrict__ tail_off,
                                             const u32* __restrict__ tail_edges,
                                             const int* __restrict__ posmap,
                                             u32* __restrict__ xout_h, float4* __restrict__ xout_f,
                                             int num_ent) {
    int wid = threadIdx.x >> 6;
    int t = blockIdx.x * 4 + wid;
    if (t >= num_ent) return;
    int lane = threadIdx.x & 63;
    int sub = lane >> 5, c = lane & 31;          // lane owns dims 4c..4c+3
    int beg = tail_off[t], end = tail_off[t + 1];
    float4 acc = make_float4(0.f, 0.f, 0.f, 0.f);
    for (int e = beg + sub; e < end; e += 2) {
        u32 w = tail_edges[e];
        int h = (int)(w & 0xFFFFu);
        int q = (int)(w >> 16);
        uint2 hw = *(const uint2*)(xh + ((size_t)h << 6) + (c << 1));
        float v0 = lo16(hw.x), v1 = hi16(hw.x), v2 = lo16(hw.y), v3 = hi16(hw.y);
        int pos = posmap[q * KF + (c >> 2)];
        if (pos >= 0) {
            float4 rv = r4[q * 16 + pos * 4 + (c & 3)];
            v0 += rv.x; v1 += rv.y; v2 += rv.z; v3 += rv.w;
        }
        acc.x += v0; acc.y += v1; acc.z += v2; acc.w += v3;
    }
    acc.x += __shfl_xor(acc.x, 32, 64);
    acc.y += __shfl_xor(acc.y, 32, 64);
    acc.z += __shfl_xor(acc.z, 32, 64);
    acc.w += __shfl_xor(acc.w, 32, 64);
    if (sub == 0) {
        uint2 sw = *(const uint2*)(xh + ((size_t)t << 6) + (c << 1));
        float inv = 1.f / (float)(end - beg + 1);
        float o0 = (acc.x + lo16(sw.x)) * inv; o0 = o0 > 0.f ? o0 : 0.f;
        float o1 = (acc.y + hi16(sw.x)) * inv; o1 = o1 > 0.f ? o1 : 0.f;
        float o2 = (acc.z + lo16(sw.y)) * inv; o2 = o2 > 0.f ? o2 : 0.f;
        float o3 = (acc.w + hi16(sw.y)) * inv; o3 = o3 > 0.f ? o3 : 0.f;
        if (OUT_BF16) {
            ((uint2*)xout_h)[((size_t)t << 5) + c] = make_uint2(pack2bf(o0, o1), pack2bf(o2, o3));
        } else {
            xout_f[((size_t)t << 5) + c] = make_float4(o0, o1, o2, o3);
        }
    }
}

// ---------------- rel pass: bf16 gathers, grid (num_rel, NS) ----------------
__global__ __launch_bounds__(256) void k_rel(const u32* __restrict__ xh,
                                             const int* __restrict__ rel_off,
                                             const u32* __restrict__ rel_edges,
                                             float* __restrict__ rsum) {
    int q = blockIdx.x;
    int s = blockIdx.y;
    int tid = threadIdx.x;
    int wid = tid >> 6, lane = tid & 63;
    int sub = lane >> 5, c = lane & 31;
    int beg = rel_off[q], end = rel_off[q + 1];
    int stride = (int)gridDim.y * 8;
    float4 acc = make_float4(0.f, 0.f, 0.f, 0.f);
    for (int e = beg + s * 8 + wid * 2 + sub; e < end; e += stride) {
        u32 w = rel_edges[e];
        int t = (int)(w & 0xFFFFu);
        int h = (int)(w >> 16);
        uint2 ta = *(const uint2*)(xh + ((size_t)t << 6) + (c << 1));
        uint2 hb = *(const uint2*)(xh + ((size_t)h << 6) + (c << 1));
        acc.x += lo16(ta.x) - lo16(hb.x);
        acc.y += hi16(ta.x) - hi16(hb.x);
        acc.z += lo16(ta.y) - lo16(hb.y);
        acc.w += hi16(ta.y) - hi16(hb.y);
    }
    acc.x += __shfl_xor(acc.x, 32, 64);
    acc.y += __shfl_xor(acc.y, 32, 64);
    acc.z += __shfl_xor(acc.z, 32, 64);
    acc.w += __shfl_xor(acc.w, 32, 64);
    __shared__ float4 part[4][32];
    if (sub == 0) part[wid][c] = acc;
    __syncthreads();
    if (tid < EMB) {
        const float* pf = (const float*)part;
        float v = pf[0 * EMB + tid] + pf[1 * EMB + tid] + pf[2 * EMB + tid] + pf[3 * EMB + tid];
        atomicAdd(&rsum[(size_t)q * EMB + tid], v);
    }
}

// ---------------- rel finalize: mean + top-4 gather ----------------
__global__ __launch_bounds__(64) void k_relfin(const float* __restrict__ rsum,
                                               const int* __restrict__ rel_off,
                                               const int* __restrict__ topmap,
                                               float* __restrict__ rout) {
    int q = blockIdx.x;
    int t = threadIdx.x;
    int cnt = rel_off[q + 1] - rel_off[q];
    int j = t >> 4, sd = t & 15;
    int k = topmap[q * TN + j];
    float v = cnt > 0 ? rsum[(size_t)q * EMB + k * SDIM + sd] / (float)cnt : 0.f;
    rout[q * (TN * SDIM) + t] = v;
}

extern "C" void kernel_launch(void* const* d_in, const int* in_sizes, int n_in,
                              void* d_out, int out_size, void* d_ws, size_t ws_size,
                              hipStream_t stream) {
    const float* x0 = (const float*)d_in[0];
    const float* r0 = (const float*)d_in[1];
    const float* rel_att = (const float*)d_in[2];
    const int* edge_index = (const int*)d_in[3];
    const int* edge_type = (const int*)d_in[4];

    const int num_ent = in_sizes[0] / EMB;
    const int num_rel = in_sizes[2] / KF;
    const int nE = in_sizes[4];

    const int* heads = edge_index;
    const int* tails = edge_index + nE;

    // ---- workspace carve-up ----
    char* base = (char*)d_ws;
    size_t off = 0;
    auto carve = [&](size_t bytes) { char* p = base + off; off = (off + bytes + 255) & ~(size_t)255; return p; };
    int* deg        = (int*)carve((size_t)num_ent * 4);
    int* tail_off   = (int*)carve((size_t)(num_ent + 1) * 4);
    int* tail_cur   = (int*)carve((size_t)num_ent * 4);
    u32* tail_edges = (u32*)carve((size_t)nE * 4);
    int* rcnt       = (int*)carve((size_t)num_rel * 4);
    int* rel_off    = (int*)carve((size_t)(num_rel + 1) * 4);
    int* rel_cur    = (int*)carve((size_t)num_rel * 4);
    u32* rel_edges  = (u32*)carve((size_t)nE * 4);
    int* posmap     = (int*)carve((size_t)num_rel * KF * 4);
    int* topmap     = (int*)carve((size_t)num_rel * TN * 4);
    u32* x0h        = (u32*)carve((size_t)num_ent * EMB * 2);   // bf16 mirror of x0
    u32* x1h        = (u32*)carve((size_t)num_ent * EMB * 2);   // bf16 layer-1 output
    float* r1       = (float*)carve((size_t)num_rel * TN * SDIM * 4);
    float* rsumA    = (float*)carve((size_t)num_rel * EMB * 4);
    float* rsumB    = (float*)carve((size_t)num_rel * EMB * 4);
    (void)ws_size;

    float* x_out = (float*)d_out;
    float* r_out = (float*)d_out + (size_t)num_ent * EMB;

    // ---- setup (layer-invariant) ----
    hipMemsetAsync(deg, 0, (size_t)num_ent * 4, stream);
    hipMemsetAsync(rcnt, 0, (size_t)num_rel * 4, stream);
    hipMemsetAsync(rsumA, 0, (size_t)num_rel * EMB * 4, stream);
    hipMemsetAsync(rsumB, 0, (size_t)num_rel * EMB * 4, stream);

    k_relmap<<<(num_rel + 63) / 64, 64, 0, stream>>>(rel_att, num_rel, posmap, topmap);
    k_hist<<<128, 256, 0, stream>>>(tails, edge_type, nE, num_rel, deg, rcnt);
    k_scan<<<1, 1024, 0, stream>>>(deg, tail_off, num_ent);
    k_scan<<<1, 1024, 0, stream>>>(rcnt, rel_off, num_rel);
    hipMemcpyAsync(tail_cur, tail_off, (size_t)num_ent * 4, hipMemcpyDeviceToDevice, stream);
    hipMemcpyAsync(rel_cur, rel_off, (size_t)num_rel * 4, hipMemcpyDeviceToDevice, stream);
    k_scatter_tail<<<512, 256, 0, stream>>>(heads, tails, edge_type, nE, num_ent, tail_cur, tail_edges);
    k_scatter_rel<<<NB, 256, 0, stream>>>(heads, tails, edge_type, nE, num_rel, rel_cur, rel_edges);
    int n4 = num_ent * 32;
    k_tobf16<<<(n4 + 255) / 256, 256, 0, stream>>>((const float4*)x0, x0h, n4);

    dim3 relgrid(num_rel, NS);
    int entgrid = (num_ent + 3) / 4;

    // ---- layer 1: x0h,r0 -> x1h (bf16), r1 ----
    k_ent<true><<<entgrid, 256, 0, stream>>>(x0h, (const float4*)r0, tail_off, tail_edges, posmap,
                                             x1h, nullptr, num_ent);
    k_rel<<<relgrid, 256, 0, stream>>>(x0h, rel_off, rel_edges, rsumA);
    k_relfin<<<num_rel, 64, 0, stream>>>(rsumA, rel_off, topmap, r1);

    // ---- layer 2: x1h,r1 -> outputs (fp32) ----
    k_ent<false><<<entgrid, 256, 0, stream>>>(x1h, (const float4*)r1, tail_off, tail_edges, posmap,
                                              nullptr, (float4*)x_out, num_ent);
    k_rel<<<relgrid, 256, 0, stream>>>(x1h, rel_off, rel_edges, rsumB);
    k_relfin<<<num_rel, 64, 0, stream>>>(rsumB, rel_off, topmap, r_out);
}

// Round 6
// 274.163 us; speedup vs baseline: 3.3418x; 1.1767x over previous
//
#include <hip/hip_runtime.h>

#define KF 8
#define TN 4
#define SDIM 16
#define EMB 128
#define NS 8     // rel-pass split factor
#define NB 128   // rel-scatter chunk count
#define NRMAX 512

typedef unsigned int u32;

// ---- bf16 helpers (manual RNE pack, bit-shift unpack) ----
__device__ __forceinline__ u32 pack2bf(float a, float b) {
    u32 ua = __float_as_uint(a), ub = __float_as_uint(b);
    ua = (ua + 0x7FFFu + ((ua >> 16) & 1u)) >> 16;
    ub = (ub + 0x7FFFu + ((ub >> 16) & 1u)) >> 16;
    return ua | (ub << 16);
}
__device__ __forceinline__ float lo16(u32 w) { return __uint_as_float(w << 16); }
__device__ __forceinline__ float hi16(u32 w) { return __uint_as_float(w & 0xFFFF0000u); }

// ---------------- fp32 -> bf16 row mirror ----------------
__global__ __launch_bounds__(256) void k_tobf16(const float4* __restrict__ x4, u32* __restrict__ xh, int n4) {
    int i = blockIdx.x * 256 + threadIdx.x;
    if (i >= n4) return;
    float4 v = x4[i];
    ((uint2*)xh)[i] = make_uint2(pack2bf(v.x, v.y), pack2bf(v.z, v.w));
}

// ---------------- per-relation top-k permutation ----------------
__global__ void k_relmap(const float* __restrict__ rel_att, int num_rel,
                         int* __restrict__ posmap, int* __restrict__ topmap) {
    int q = blockIdx.x * blockDim.x + threadIdx.x;
    if (q >= num_rel) return;
    float v[KF]; int idx[KF];
    for (int k = 0; k < KF; ++k) { v[k] = rel_att[q * KF + k]; idx[k] = k; }
    for (int i = 1; i < KF; ++i) {
        float vi = v[i]; int ii = idx[i]; int j = i - 1;
        while (j >= 0 && v[j] < vi) { v[j + 1] = v[j]; idx[j + 1] = idx[j]; --j; }
        v[j + 1] = vi; idx[j + 1] = ii;
    }
    int pos[KF];
    for (int k = 0; k < KF; ++k) pos[k] = -1;
    for (int j = 0; j < TN; ++j) { topmap[q * TN + j] = idx[j]; pos[idx[j]] = j; }
    for (int k = 0; k < KF; ++k) posmap[q * KF + k] = pos[k];
}

// ---------------- permuted-rel bf16 table: pr[q][dim] = pos>=0 ? r[q][pos*16+dim%16] : 0 ----------------
__global__ __launch_bounds__(64) void k_mkpr(const float* __restrict__ r, const int* __restrict__ posmap,
                                             u32* __restrict__ prh, int num_rel) {
    int q = blockIdx.x;
    if (q >= num_rel) return;
    int i = threadIdx.x;                 // word i covers dims 2i, 2i+1 (same factor)
    int k = i >> 3;
    int pos = posmap[q * KF + k];
    u32 w = 0;
    if (pos >= 0) {
        float a = r[q * 64 + pos * SDIM + ((2 * i) & 15)];
        float b = r[q * 64 + pos * SDIM + ((2 * i + 1) & 15)];
        w = pack2bf(a, b);
    }
    prh[q * 64 + i] = w;
}

// ---------------- histograms ----------------
__global__ __launch_bounds__(256) void k_hist(const int* __restrict__ tails, const int* __restrict__ types,
                                              int nE, int num_rel,
                                              int* __restrict__ deg, int* __restrict__ rcnt) {
    __shared__ int hist[NRMAX];
    for (int q = threadIdx.x; q < num_rel; q += 256) hist[q] = 0;
    __syncthreads();
    for (int i = blockIdx.x * 256 + threadIdx.x; i < nE; i += gridDim.x * 256) {
        atomicAdd(&deg[tails[i]], 1);
        atomicAdd(&hist[types[i]], 1);
    }
    __syncthreads();
    for (int q = threadIdx.x; q < num_rel; q += 256) {
        int h = hist[q];
        if (h) atomicAdd(&rcnt[q], h);
    }
}

// ---------------- single-block exclusive scan ----------------
__global__ void k_scan(const int* __restrict__ in, int* __restrict__ out, int n) {
    __shared__ int warp_sums[16];
    int carry = 0;
    int lane = threadIdx.x & 63, wid = threadIdx.x >> 6;
    int nw = blockDim.x >> 6;
    for (int base = 0; base < n; base += blockDim.x) {
        int i = base + (int)threadIdx.x;
        int v = (i < n) ? in[i] : 0;
        int sv = v;
        for (int o = 1; o < 64; o <<= 1) { int t = __shfl_up(sv, o, 64); if (lane >= o) sv += t; }
        if (lane == 63) warp_sums[wid] = sv;
        __syncthreads();
        if (wid == 0 && lane < nw) {
            int ws = warp_sums[lane];
            for (int o = 1; o < 16; o <<= 1) { int t = __shfl_up(ws, o, 64); if (lane >= o) ws += t; }
            warp_sums[lane] = ws;
        }
        __syncthreads();
        int wofs = (wid > 0) ? warp_sums[wid - 1] : 0;
        int total = warp_sums[nw - 1];
        if (i < n) out[i] = carry + wofs + sv - v;
        carry += total;
        __syncthreads();
    }
    if (threadIdx.x == 0) out[n] = carry;
}

// ---------------- tail CSR scatter: XCD-partitioned by tail range ----------------
__global__ __launch_bounds__(256) void k_scatter_tail(const int* __restrict__ heads,
                                                      const int* __restrict__ tails,
                                                      const int* __restrict__ types,
                                                      int nE, int num_ent,
                                                      int* __restrict__ tail_cur,
                                                      u32* __restrict__ tail_edges) {
    int bi = blockIdx.x;
    int xcd = bi & 7;
    int w = bi >> 3;
    int nw = gridDim.x >> 3;
    int per = (num_ent + 7) >> 3;
    int lo = xcd * per, hi = min(lo + per, num_ent);
    for (int i = w * 256 + (int)threadIdx.x; i < nE; i += nw * 256) {
        int t = tails[i];
        if (t >= lo && t < hi) {
            int p = atomicAdd(&tail_cur[t], 1);
            tail_edges[p] = (u32)heads[i] | ((u32)types[i] << 16);
        }
    }
}

// ---------------- rel CSR scatter: LDS hist -> block-granular reservation -> LDS ranks ----------------
__global__ __launch_bounds__(256) void k_scatter_rel(const int* __restrict__ heads,
                                                     const int* __restrict__ tails,
                                                     const int* __restrict__ types,
                                                     int nE, int num_rel,
                                                     int* __restrict__ rel_cur,
                                                     u32* __restrict__ rel_edges) {
    __shared__ int hist[NRMAX];
    __shared__ int base[NRMAX];
    int bi = blockIdx.x;
    int c = (bi & 7) * (NB >> 3) + (bi >> 3);
    int chunk = (nE + NB - 1) / NB;
    int beg = c * chunk, end = min(beg + chunk, nE);
    for (int q = threadIdx.x; q < num_rel; q += 256) hist[q] = 0;
    __syncthreads();
    for (int i = beg + (int)threadIdx.x; i < end; i += 256) atomicAdd(&hist[types[i]], 1);
    __syncthreads();
    for (int q = threadIdx.x; q < num_rel; q += 256) {
        int h = hist[q];
        base[q] = h > 0 ? atomicAdd(&rel_cur[q], h) : 0;
        hist[q] = 0;
    }
    __syncthreads();
    for (int i = beg + (int)threadIdx.x; i < end; i += 256) {
        int q = types[i];
        int rank = atomicAdd(&hist[q], 1);
        rel_edges[base[q] + rank] = (u32)tails[i] | ((u32)heads[i] << 16);
    }
}

// ---------------- ent pass: quarter-wave uint4 gathers, batched edge prefetch ----------------
// wave = 1 tail; lane = 16*qw + c; lane owns dims 8c..8c+7; 4 edges in flight/iter
template <bool OUT_BF16>
__global__ __launch_bounds__(256) void k_ent(const u32* __restrict__ xh, const u32* __restrict__ prh,
                                             const int* __restrict__ tail_off,
                                             const u32* __restrict__ tail_edges,
                                             u32* __restrict__ xout_h, float4* __restrict__ xout_f,
                                             int num_ent) {
    int wid = threadIdx.x >> 6;
    int t = blockIdx.x * 4 + wid;
    if (t >= num_ent) return;
    int lane = threadIdx.x & 63;
    int qw = lane >> 4, c = lane & 15;
    int beg = tail_off[t], end = tail_off[t + 1];
    int deg = end - beg;
    float acc[8] = {0.f, 0.f, 0.f, 0.f, 0.f, 0.f, 0.f, 0.f};
    for (int b2 = 0; b2 < deg; b2 += 64) {
        int m = min(64, deg - b2);
        u32 ew = (lane < m) ? tail_edges[beg + b2 + lane] : 0u;   // coalesced batch prefetch
        for (int j = 0; j < m; j += 4) {
            int idx = j + qw;
            u32 w = __shfl(ew, idx, 64);
            uint4 xr = make_uint4(0, 0, 0, 0), pr = make_uint4(0, 0, 0, 0);
            if (idx < m) {
                int h = (int)(w & 0xFFFFu);
                int q = (int)(w >> 16);
                xr = *(const uint4*)(xh + ((size_t)h << 6) + (c << 2));
                pr = *(const uint4*)(prh + ((size_t)q << 6) + (c << 2));
            }
            acc[0] += lo16(xr.x) + lo16(pr.x);
            acc[1] += hi16(xr.x) + hi16(pr.x);
            acc[2] += lo16(xr.y) + lo16(pr.y);
            acc[3] += hi16(xr.y) + hi16(pr.y);
            acc[4] += lo16(xr.z) + lo16(pr.z);
            acc[5] += hi16(xr.z) + hi16(pr.z);
            acc[6] += lo16(xr.w) + lo16(pr.w);
            acc[7] += hi16(xr.w) + hi16(pr.w);
        }
    }
#pragma unroll
    for (int d = 0; d < 8; ++d) {
        acc[d] += __shfl_xor(acc[d], 16, 64);
        acc[d] += __shfl_xor(acc[d], 32, 64);
    }
    if (qw == 0) {
        uint4 sw = *(const uint4*)(xh + ((size_t)t << 6) + (c << 2));   // self-loop row
        float s[8] = { lo16(sw.x), hi16(sw.x), lo16(sw.y), hi16(sw.y),
                       lo16(sw.z), hi16(sw.z), lo16(sw.w), hi16(sw.w) };
        float inv = 1.f / (float)(deg + 1);
        float o[8];
#pragma unroll
        for (int d = 0; d < 8; ++d) {
            float v = (acc[d] + s[d]) * inv;
            o[d] = v > 0.f ? v : 0.f;
        }
        if (OUT_BF16) {
            uint4 ow = make_uint4(pack2bf(o[0], o[1]), pack2bf(o[2], o[3]),
                                  pack2bf(o[4], o[5]), pack2bf(o[6], o[7]));
            *(uint4*)(xout_h + ((size_t)t << 6) + (c << 2)) = ow;
        } else {
            xout_f[((size_t)t << 5) + (c << 1)]     = make_float4(o[0], o[1], o[2], o[3]);
            xout_f[((size_t)t << 5) + (c << 1) + 1] = make_float4(o[4], o[5], o[6], o[7]);
        }
    }
}

// ---------------- rel pass: bf16 gathers, grid (num_rel, NS) ----------------
__global__ __launch_bounds__(256) void k_rel(const u32* __restrict__ xh,
                                             const int* __restrict__ rel_off,
                                             const u32* __restrict__ rel_edges,
                                             float* __restrict__ rsum) {
    int q = blockIdx.x;
    int s = blockIdx.y;
    int tid = threadIdx.x;
    int wid = tid >> 6, lane = tid & 63;
    int sub = lane >> 5, c = lane & 31;
    int beg = rel_off[q], end = rel_off[q + 1];
    int stride = (int)gridDim.y * 8;
    float4 acc = make_float4(0.f, 0.f, 0.f, 0.f);
    for (int e = beg + s * 8 + wid * 2 + sub; e < end; e += stride) {
        u32 w = rel_edges[e];
        int t = (int)(w & 0xFFFFu);
        int h = (int)(w >> 16);
        uint2 ta = *(const uint2*)(xh + ((size_t)t << 6) + (c << 1));
        uint2 hb = *(const uint2*)(xh + ((size_t)h << 6) + (c << 1));
        acc.x += lo16(ta.x) - lo16(hb.x);
        acc.y += hi16(ta.x) - hi16(hb.x);
        acc.z += lo16(ta.y) - lo16(hb.y);
        acc.w += hi16(ta.y) - hi16(hb.y);
    }
    acc.x += __shfl_xor(acc.x, 32, 64);
    acc.y += __shfl_xor(acc.y, 32, 64);
    acc.z += __shfl_xor(acc.z, 32, 64);
    acc.w += __shfl_xor(acc.w, 32, 64);
    __shared__ float4 part[4][32];
    if (sub == 0) part[wid][c] = acc;
    __syncthreads();
    if (tid < EMB) {
        const float* pf = (const float*)part;
        float v = pf[0 * EMB + tid] + pf[1 * EMB + tid] + pf[2 * EMB + tid] + pf[3 * EMB + tid];
        atomicAdd(&rsum[(size_t)q * EMB + tid], v);
    }
}

// ---------------- rel finalize: mean + top-4 gather ----------------
__global__ __launch_bounds__(64) void k_relfin(const float* __restrict__ rsum,
                                               const int* __restrict__ rel_off,
                                               const int* __restrict__ topmap,
                                               float* __restrict__ rout) {
    int q = blockIdx.x;
    int t = threadIdx.x;
    int cnt = rel_off[q + 1] - rel_off[q];
    int j = t >> 4, sd = t & 15;
    int k = topmap[q * TN + j];
    float v = cnt > 0 ? rsum[(size_t)q * EMB + k * SDIM + sd] / (float)cnt : 0.f;
    rout[q * (TN * SDIM) + t] = v;
}

extern "C" void kernel_launch(void* const* d_in, const int* in_sizes, int n_in,
                              void* d_out, int out_size, void* d_ws, size_t ws_size,
                              hipStream_t stream) {
    const float* x0 = (const float*)d_in[0];
    const float* r0 = (const float*)d_in[1];
    const float* rel_att = (const float*)d_in[2];
    const int* edge_index = (const int*)d_in[3];
    const int* edge_type = (const int*)d_in[4];

    const int num_ent = in_sizes[0] / EMB;
    const int num_rel = in_sizes[2] / KF;
    const int nE = in_sizes[4];

    const int* heads = edge_index;
    const int* tails = edge_index + nE;

    // ---- workspace carve-up ----
    char* base = (char*)d_ws;
    size_t off = 0;
    auto carve = [&](size_t bytes) { char* p = base + off; off = (off + bytes + 255) & ~(size_t)255; return p; };
    int* deg        = (int*)carve((size_t)num_ent * 4);
    int* tail_off   = (int*)carve((size_t)(num_ent + 1) * 4);
    int* tail_cur   = (int*)carve((size_t)num_ent * 4);
    u32* tail_edges = (u32*)carve((size_t)nE * 4);
    int* rcnt       = (int*)carve((size_t)num_rel * 4);
    int* rel_off    = (int*)carve((size_t)(num_rel + 1) * 4);
    int* rel_cur    = (int*)carve((size_t)num_rel * 4);
    u32* rel_edges  = (u32*)carve((size_t)nE * 4);
    int* posmap     = (int*)carve((size_t)num_rel * KF * 4);
    int* topmap     = (int*)carve((size_t)num_rel * TN * 4);
    u32* x0h        = (u32*)carve((size_t)num_ent * EMB * 2);   // bf16 mirror of x0
    u32* x1h        = (u32*)carve((size_t)num_ent * EMB * 2);   // bf16 layer-1 output
    u32* pr0        = (u32*)carve((size_t)num_rel * 64 * 4);    // permuted rel bf16, layer 1
    u32* pr1        = (u32*)carve((size_t)num_rel * 64 * 4);    // permuted rel bf16, layer 2
    float* r1       = (float*)carve((size_t)num_rel * TN * SDIM * 4);
    float* rsumA    = (float*)carve((size_t)num_rel * EMB * 4);
    float* rsumB    = (float*)carve((size_t)num_rel * EMB * 4);
    (void)ws_size;

    float* x_out = (float*)d_out;
    float* r_out = (float*)d_out + (size_t)num_ent * EMB;

    // ---- setup (layer-invariant) ----
    hipMemsetAsync(deg, 0, (size_t)num_ent * 4, stream);
    hipMemsetAsync(rcnt, 0, (size_t)num_rel * 4, stream);
    hipMemsetAsync(rsumA, 0, (size_t)num_rel * EMB * 4, stream);
    hipMemsetAsync(rsumB, 0, (size_t)num_rel * EMB * 4, stream);

    k_relmap<<<(num_rel + 63) / 64, 64, 0, stream>>>(rel_att, num_rel, posmap, topmap);
    k_mkpr<<<num_rel, 64, 0, stream>>>(r0, posmap, pr0, num_rel);
    k_hist<<<128, 256, 0, stream>>>(tails, edge_type, nE, num_rel, deg, rcnt);
    k_scan<<<1, 1024, 0, stream>>>(deg, tail_off, num_ent);
    k_scan<<<1, 1024, 0, stream>>>(rcnt, rel_off, num_rel);
    hipMemcpyAsync(tail_cur, tail_off, (size_t)num_ent * 4, hipMemcpyDeviceToDevice, stream);
    hipMemcpyAsync(rel_cur, rel_off, (size_t)num_rel * 4, hipMemcpyDeviceToDevice, stream);
    k_scatter_tail<<<512, 256, 0, stream>>>(heads, tails, edge_type, nE, num_ent, tail_cur, tail_edges);
    k_scatter_rel<<<NB, 256, 0, stream>>>(heads, tails, edge_type, nE, num_rel, rel_cur, rel_edges);
    int n4 = num_ent * 32;
    k_tobf16<<<(n4 + 255) / 256, 256, 0, stream>>>((const float4*)x0, x0h, n4);

    dim3 relgrid(num_rel, NS);
    int entgrid = (num_ent + 3) / 4;

    // ---- layer 1: x0h,pr0 -> x1h (bf16), r1 ----
    k_ent<true><<<entgrid, 256, 0, stream>>>(x0h, pr0, tail_off, tail_edges, x1h, nullptr, num_ent);
    k_rel<<<relgrid, 256, 0, stream>>>(x0h, rel_off, rel_edges, rsumA);
    k_relfin<<<num_rel, 64, 0, stream>>>(rsumA, rel_off, topmap, r1);
    k_mkpr<<<num_rel, 64, 0, stream>>>(r1, posmap, pr1, num_rel);

    // ---- layer 2: x1h,pr1 -> outputs (fp32) ----
    k_ent<false><<<entgrid, 256, 0, stream>>>(x1h, pr1, tail_off, tail_edges, nullptr, (float4*)x_out, num_ent);
    k_rel<<<relgrid, 256, 0, stream>>>(x1h, rel_off, rel_edges, rsumB);
    k_relfin<<<num_rel, 64, 0, stream>>>(rsumB, rel_off, topmap, r_out);
}

// Round 7
// 231.131 us; speedup vs baseline: 3.9640x; 1.1862x over previous
//
#include <hip/hip_runtime.h>

#define KF 8
#define TN 4
#define SDIM 16
#define EMB 128
#define NS 8     // rel-pass split factor
#define NB 128   // rel-scatter chunk count
#define NRMAX 512
#define SCE 1024 // elements per scan block

typedef unsigned int u32;

// ---- bf16 helpers (manual RNE pack, bit-shift unpack) ----
__device__ __forceinline__ u32 pack2bf(float a, float b) {
    u32 ua = __float_as_uint(a), ub = __float_as_uint(b);
    ua = (ua + 0x7FFFu + ((ua >> 16) & 1u)) >> 16;
    ub = (ub + 0x7FFFu + ((ub >> 16) & 1u)) >> 16;
    return ua | (ub << 16);
}
__device__ __forceinline__ float lo16(u32 w) { return __uint_as_float(w << 16); }
__device__ __forceinline__ float hi16(u32 w) { return __uint_as_float(w & 0xFFFF0000u); }

// ---------------- fp32 -> bf16 row mirror ----------------
__global__ __launch_bounds__(256) void k_tobf16(const float4* __restrict__ x4, u32* __restrict__ xh, int n4) {
    int i = blockIdx.x * 256 + threadIdx.x;
    if (i >= n4) return;
    float4 v = x4[i];
    ((uint2*)xh)[i] = make_uint2(pack2bf(v.x, v.y), pack2bf(v.z, v.w));
}

// ---------------- per-relation top-k permutation ----------------
__global__ void k_relmap(const float* __restrict__ rel_att, int num_rel,
                         int* __restrict__ posmap, int* __restrict__ topmap) {
    int q = blockIdx.x * blockDim.x + threadIdx.x;
    if (q >= num_rel) return;
    float v[KF]; int idx[KF];
    for (int k = 0; k < KF; ++k) { v[k] = rel_att[q * KF + k]; idx[k] = k; }
    for (int i = 1; i < KF; ++i) {
        float vi = v[i]; int ii = idx[i]; int j = i - 1;
        while (j >= 0 && v[j] < vi) { v[j + 1] = v[j]; idx[j + 1] = idx[j]; --j; }
        v[j + 1] = vi; idx[j + 1] = ii;
    }
    int pos[KF];
    for (int k = 0; k < KF; ++k) pos[k] = -1;
    for (int j = 0; j < TN; ++j) { topmap[q * TN + j] = idx[j]; pos[idx[j]] = j; }
    for (int k = 0; k < KF; ++k) posmap[q * KF + k] = pos[k];
}

// ---------------- permuted-rel bf16 table from fp32 r (layer 1 input) ----------------
__global__ __launch_bounds__(64) void k_mkpr(const float* __restrict__ r, const int* __restrict__ posmap,
                                             u32* __restrict__ prh, int num_rel) {
    int q = blockIdx.x;
    if (q >= num_rel) return;
    int i = threadIdx.x;                 // word i covers dims 2i, 2i+1 (same factor)
    int k = i >> 3;
    int pos = posmap[q * KF + k];
    u32 w = 0;
    if (pos >= 0) {
        float a = r[q * 64 + pos * SDIM + ((2 * i) & 15)];
        float b = r[q * 64 + pos * SDIM + ((2 * i + 1) & 15)];
        w = pack2bf(a, b);
    }
    prh[q * 64 + i] = w;
}

// ---------------- histograms ----------------
__global__ __launch_bounds__(256) void k_hist(const int* __restrict__ tails, const int* __restrict__ types,
                                              int nE, int num_rel,
                                              int* __restrict__ deg, int* __restrict__ rcnt) {
    __shared__ int hist[NRMAX];
    for (int q = threadIdx.x; q < num_rel; q += 256) hist[q] = 0;
    __syncthreads();
    for (int i = blockIdx.x * 256 + threadIdx.x; i < nE; i += gridDim.x * 256) {
        atomicAdd(&deg[tails[i]], 1);
        atomicAdd(&hist[types[i]], 1);
    }
    __syncthreads();
    for (int q = threadIdx.x; q < num_rel; q += 256) {
        int h = hist[q];
        if (h) atomicAdd(&rcnt[q], h);
    }
}

// ---------------- single-block exclusive scan (small n / block sums); optional dup out2 ----------------
__global__ void k_scan(const int* __restrict__ in, int* __restrict__ out, int* __restrict__ out2, int n) {
    __shared__ int warp_sums[16];
    int carry = 0;
    int lane = threadIdx.x & 63, wid = threadIdx.x >> 6;
    int nw = blockDim.x >> 6;
    for (int base = 0; base < n; base += blockDim.x) {
        int i = base + (int)threadIdx.x;
        int v = (i < n) ? in[i] : 0;
        int sv = v;
        for (int o = 1; o < 64; o <<= 1) { int t = __shfl_up(sv, o, 64); if (lane >= o) sv += t; }
        if (lane == 63) warp_sums[wid] = sv;
        __syncthreads();
        if (wid == 0 && lane < nw) {
            int ws = warp_sums[lane];
            for (int o = 1; o < 16; o <<= 1) { int t = __shfl_up(ws, o, 64); if (lane >= o) ws += t; }
            warp_sums[lane] = ws;
        }
        __syncthreads();
        int wofs = (wid > 0) ? warp_sums[wid - 1] : 0;
        int total = warp_sums[nw - 1];
        if (i < n) {
            int e = carry + wofs + sv - v;
            out[i] = e;
            if (out2) out2[i] = e;
        }
        carry += total;
        __syncthreads();
    }
    if (threadIdx.x == 0) out[n] = carry;
}

// ---------------- hierarchical scan phase 1: per-block local exclusive scan + block sums ----------------
__global__ __launch_bounds__(256) void k_scan1(const int* __restrict__ in, int* __restrict__ out,
                                               int* __restrict__ bsum, int n) {
    __shared__ int warp_sums[4];
    int blk = blockIdx.x;
    int i0 = blk * SCE + (int)threadIdx.x * 4;
    int v[4];
#pragma unroll
    for (int j = 0; j < 4; ++j) { int i = i0 + j; v[j] = (i < n) ? in[i] : 0; }
    int tsum = v[0] + v[1] + v[2] + v[3];
    int lane = threadIdx.x & 63, wid = threadIdx.x >> 6;
    int sv = tsum;
    for (int o = 1; o < 64; o <<= 1) { int t = __shfl_up(sv, o, 64); if (lane >= o) sv += t; }
    if (lane == 63) warp_sums[wid] = sv;
    __syncthreads();
    if (threadIdx.x == 0) {
        int s = 0;
        for (int w = 0; w < 4; ++w) { int t = warp_sums[w]; warp_sums[w] = s; s += t; }
        bsum[blk] = s;
    }
    __syncthreads();
    int run = warp_sums[wid] + sv - tsum;
#pragma unroll
    for (int j = 0; j < 4; ++j) { int i = i0 + j; if (i < n) out[i] = run; run += v[j]; }
}

// ---------------- hierarchical scan phase 3: add block offsets, dup to cur ----------------
__global__ __launch_bounds__(256) void k_scan2(int* __restrict__ out, int* __restrict__ out2,
                                               const int* __restrict__ bofs, int n, int nblk) {
    int blk = blockIdx.x;
    int add = bofs[blk];
    int i0 = blk * SCE + (int)threadIdx.x * 4;
#pragma unroll
    for (int j = 0; j < 4; ++j) {
        int i = i0 + j;
        if (i < n) { int val = out[i] + add; out[i] = val; out2[i] = val; }
    }
    if (blk == 0 && threadIdx.x == 0) out[n] = bofs[nblk];
}

// ---------------- tail CSR scatter: XCD-partitioned by tail range ----------------
__global__ __launch_bounds__(256) void k_scatter_tail(const int* __restrict__ heads,
                                                      const int* __restrict__ tails,
                                                      const int* __restrict__ types,
                                                      int nE, int num_ent,
                                                      int* __restrict__ tail_cur,
                                                      u32* __restrict__ tail_edges) {
    int bi = blockIdx.x;
    int xcd = bi & 7;
    int w = bi >> 3;
    int nw = gridDim.x >> 3;
    int per = (num_ent + 7) >> 3;
    int lo = xcd * per, hi = min(lo + per, num_ent);
    for (int i = w * 256 + (int)threadIdx.x; i < nE; i += nw * 256) {
        int t = tails[i];
        if (t >= lo && t < hi) {
            int p = atomicAdd(&tail_cur[t], 1);
            tail_edges[p] = (u32)heads[i] | ((u32)types[i] << 16);
        }
    }
}

// ---------------- rel CSR scatter: LDS hist -> block-granular reservation -> LDS ranks ----------------
__global__ __launch_bounds__(256) void k_scatter_rel(const int* __restrict__ heads,
                                                     const int* __restrict__ tails,
                                                     const int* __restrict__ types,
                                                     int nE, int num_rel,
                                                     int* __restrict__ rel_cur,
                                                     u32* __restrict__ rel_edges) {
    __shared__ int hist[NRMAX];
    __shared__ int base[NRMAX];
    int bi = blockIdx.x;
    int c = (bi & 7) * (NB >> 3) + (bi >> 3);
    int chunk = (nE + NB - 1) / NB;
    int beg = c * chunk, end = min(beg + chunk, nE);
    for (int q = threadIdx.x; q < num_rel; q += 256) hist[q] = 0;
    __syncthreads();
    for (int i = beg + (int)threadIdx.x; i < end; i += 256) atomicAdd(&hist[types[i]], 1);
    __syncthreads();
    for (int q = threadIdx.x; q < num_rel; q += 256) {
        int h = hist[q];
        base[q] = h > 0 ? atomicAdd(&rel_cur[q], h) : 0;
        hist[q] = 0;
    }
    __syncthreads();
    for (int i = beg + (int)threadIdx.x; i < end; i += 256) {
        int q = types[i];
        int rank = atomicAdd(&hist[q], 1);
        rel_edges[base[q] + rank] = (u32)tails[i] | ((u32)heads[i] << 16);
    }
}

// ---------------- ent pass: quarter-wave uint4 gathers, batched edge prefetch ----------------
template <bool OUT_BF16>
__global__ __launch_bounds__(256) void k_ent(const u32* __restrict__ xh, const u32* __restrict__ prh,
                                             const int* __restrict__ tail_off,
                                             const u32* __restrict__ tail_edges,
                                             u32* __restrict__ xout_h, float4* __restrict__ xout_f,
                                             int num_ent) {
    int wid = threadIdx.x >> 6;
    int t = blockIdx.x * 4 + wid;
    if (t >= num_ent) return;
    int lane = threadIdx.x & 63;
    int qw = lane >> 4, c = lane & 15;
    int beg = tail_off[t], end = tail_off[t + 1];
    int deg = end - beg;
    float acc[8] = {0.f, 0.f, 0.f, 0.f, 0.f, 0.f, 0.f, 0.f};
    for (int b2 = 0; b2 < deg; b2 += 64) {
        int m = min(64, deg - b2);
        u32 ew = (lane < m) ? tail_edges[beg + b2 + lane] : 0u;
        for (int j = 0; j < m; j += 4) {
            int idx = j + qw;
            u32 w = __shfl(ew, idx, 64);
            uint4 xr = make_uint4(0, 0, 0, 0), pr = make_uint4(0, 0, 0, 0);
            if (idx < m) {
                int h = (int)(w & 0xFFFFu);
                int q = (int)(w >> 16);
                xr = *(const uint4*)(xh + ((size_t)h << 6) + (c << 2));
                pr = *(const uint4*)(prh + ((size_t)q << 6) + (c << 2));
            }
            acc[0] += lo16(xr.x) + lo16(pr.x);
            acc[1] += hi16(xr.x) + hi16(pr.x);
            acc[2] += lo16(xr.y) + lo16(pr.y);
            acc[3] += hi16(xr.y) + hi16(pr.y);
            acc[4] += lo16(xr.z) + lo16(pr.z);
            acc[5] += hi16(xr.z) + hi16(pr.z);
            acc[6] += lo16(xr.w) + lo16(pr.w);
            acc[7] += hi16(xr.w) + hi16(pr.w);
        }
    }
#pragma unroll
    for (int d = 0; d < 8; ++d) {
        acc[d] += __shfl_xor(acc[d], 16, 64);
        acc[d] += __shfl_xor(acc[d], 32, 64);
    }
    if (qw == 0) {
        uint4 sw = *(const uint4*)(xh + ((size_t)t << 6) + (c << 2));
        float s[8] = { lo16(sw.x), hi16(sw.x), lo16(sw.y), hi16(sw.y),
                       lo16(sw.z), hi16(sw.z), lo16(sw.w), hi16(sw.w) };
        float inv = 1.f / (float)(deg + 1);
        float o[8];
#pragma unroll
        for (int d = 0; d < 8; ++d) {
            float v = (acc[d] + s[d]) * inv;
            o[d] = v > 0.f ? v : 0.f;
        }
        if (OUT_BF16) {
            uint4 ow = make_uint4(pack2bf(o[0], o[1]), pack2bf(o[2], o[3]),
                                  pack2bf(o[4], o[5]), pack2bf(o[6], o[7]));
            *(uint4*)(xout_h + ((size_t)t << 6) + (c << 2)) = ow;
        } else {
            xout_f[((size_t)t << 5) + (c << 1)]     = make_float4(o[0], o[1], o[2], o[3]);
            xout_f[((size_t)t << 5) + (c << 1) + 1] = make_float4(o[4], o[5], o[6], o[7]);
        }
    }
}

// ---------------- rel pass: bf16 gathers, grid (num_rel, NS) ----------------
__global__ __launch_bounds__(256) void k_rel(const u32* __restrict__ xh,
                                             const int* __restrict__ rel_off,
                                             const u32* __restrict__ rel_edges,
                                             float* __restrict__ rsum) {
    int q = blockIdx.x;
    int s = blockIdx.y;
    int tid = threadIdx.x;
    int wid = tid >> 6, lane = tid & 63;
    int sub = lane >> 5, c = lane & 31;
    int beg = rel_off[q], end = rel_off[q + 1];
    int stride = (int)gridDim.y * 8;
    float4 acc = make_float4(0.f, 0.f, 0.f, 0.f);
    for (int e = beg + s * 8 + wid * 2 + sub; e < end; e += stride) {
        u32 w = rel_edges[e];
        int t = (int)(w & 0xFFFFu);
        int h = (int)(w >> 16);
        uint2 ta = *(const uint2*)(xh + ((size_t)t << 6) + (c << 1));
        uint2 hb = *(const uint2*)(xh + ((size_t)h << 6) + (c << 1));
        acc.x += lo16(ta.x) - lo16(hb.x);
        acc.y += hi16(ta.x) - hi16(hb.x);
        acc.z += lo16(ta.y) - lo16(hb.y);
        acc.w += hi16(ta.y) - hi16(hb.y);
    }
    acc.x += __shfl_xor(acc.x, 32, 64);
    acc.y += __shfl_xor(acc.y, 32, 64);
    acc.z += __shfl_xor(acc.z, 32, 64);
    acc.w += __shfl_xor(acc.w, 32, 64);
    __shared__ float4 part[4][32];
    if (sub == 0) part[wid][c] = acc;
    __syncthreads();
    if (tid < EMB) {
        const float* pf = (const float*)part;
        float v = pf[0 * EMB + tid] + pf[1 * EMB + tid] + pf[2 * EMB + tid] + pf[3 * EMB + tid];
        atomicAdd(&rsum[(size_t)q * EMB + tid], v);
    }
}

// ---------------- layer-1 fused: rel mean -> permuted bf16 table (permutation cancels) ----------------
__global__ __launch_bounds__(64) void k_relfin_pr(const float* __restrict__ rsum,
                                                  const int* __restrict__ rel_off,
                                                  const int* __restrict__ posmap,
                                                  u32* __restrict__ prh, int num_rel) {
    int q = blockIdx.x;
    if (q >= num_rel) return;
    int i = threadIdx.x;                 // word i covers dims 2i, 2i+1
    int k = i >> 3;
    int pos = posmap[q * KF + k];
    int cnt = rel_off[q + 1] - rel_off[q];
    u32 w = 0;
    if (pos >= 0 && cnt > 0) {
        float inv = 1.f / (float)cnt;
        w = pack2bf(rsum[(size_t)q * EMB + 2 * i] * inv, rsum[(size_t)q * EMB + 2 * i + 1] * inv);
    }
    prh[q * 64 + i] = w;
}

// ---------------- rel finalize (layer 2): mean + top-4 gather ----------------
__global__ __launch_bounds__(64) void k_relfin(const float* __restrict__ rsum,
                                               const int* __restrict__ rel_off,
                                               const int* __restrict__ topmap,
                                               float* __restrict__ rout) {
    int q = blockIdx.x;
    int t = threadIdx.x;
    int cnt = rel_off[q + 1] - rel_off[q];
    int j = t >> 4, sd = t & 15;
    int k = topmap[q * TN + j];
    float v = cnt > 0 ? rsum[(size_t)q * EMB + k * SDIM + sd] / (float)cnt : 0.f;
    rout[q * (TN * SDIM) + t] = v;
}

extern "C" void kernel_launch(void* const* d_in, const int* in_sizes, int n_in,
                              void* d_out, int out_size, void* d_ws, size_t ws_size,
                              hipStream_t stream) {
    const float* x0 = (const float*)d_in[0];
    const float* r0 = (const float*)d_in[1];
    const float* rel_att = (const float*)d_in[2];
    const int* edge_index = (const int*)d_in[3];
    const int* edge_type = (const int*)d_in[4];

    const int num_ent = in_sizes[0] / EMB;
    const int num_rel = in_sizes[2] / KF;
    const int nE = in_sizes[4];

    const int* heads = edge_index;
    const int* tails = edge_index + nE;

    const int nblk = (num_ent + SCE - 1) / SCE;

    // ---- workspace carve-up ----
    char* base = (char*)d_ws;
    size_t off = 0;
    auto carve = [&](size_t bytes) { char* p = base + off; off = (off + bytes + 255) & ~(size_t)255; return p; };
    int* deg        = (int*)carve((size_t)num_ent * 4);
    int* tail_off   = (int*)carve((size_t)(num_ent + 1) * 4);
    int* tail_cur   = (int*)carve((size_t)num_ent * 4);
    u32* tail_edges = (u32*)carve((size_t)nE * 4);
    int* rcnt       = (int*)carve((size_t)num_rel * 4);
    int* rel_off    = (int*)carve((size_t)(num_rel + 1) * 4);
    int* rel_cur    = (int*)carve((size_t)num_rel * 4);
    u32* rel_edges  = (u32*)carve((size_t)nE * 4);
    int* posmap     = (int*)carve((size_t)num_rel * KF * 4);
    int* topmap     = (int*)carve((size_t)num_rel * TN * 4);
    int* bsum       = (int*)carve((size_t)nblk * 4);
    int* bofs       = (int*)carve((size_t)(nblk + 1) * 4);
    u32* x0h        = (u32*)carve((size_t)num_ent * EMB * 2);   // bf16 mirror of x0
    u32* x1h        = (u32*)carve((size_t)num_ent * EMB * 2);   // bf16 layer-1 output
    u32* pr0        = (u32*)carve((size_t)num_rel * 64 * 4);    // permuted rel bf16, layer 1
    u32* pr1        = (u32*)carve((size_t)num_rel * 64 * 4);    // permuted rel bf16, layer 2
    float* rsumA    = (float*)carve((size_t)num_rel * EMB * 4);
    float* rsumB    = (float*)carve((size_t)num_rel * EMB * 4);
    (void)ws_size;

    float* x_out = (float*)d_out;
    float* r_out = (float*)d_out + (size_t)num_ent * EMB;

    // ---- setup (layer-invariant) ----
    hipMemsetAsync(deg, 0, (size_t)num_ent * 4, stream);
    hipMemsetAsync(rcnt, 0, (size_t)num_rel * 4, stream);
    hipMemsetAsync(rsumA, 0, (size_t)num_rel * EMB * 4, stream);
    hipMemsetAsync(rsumB, 0, (size_t)num_rel * EMB * 4, stream);

    k_relmap<<<(num_rel + 63) / 64, 64, 0, stream>>>(rel_att, num_rel, posmap, topmap);
    k_mkpr<<<num_rel, 64, 0, stream>>>(r0, posmap, pr0, num_rel);
    k_hist<<<256, 256, 0, stream>>>(tails, edge_type, nE, num_rel, deg, rcnt);
    // hierarchical scan: deg -> tail_off (+ tail_cur)
    k_scan1<<<nblk, 256, 0, stream>>>(deg, tail_off, bsum, num_ent);
    k_scan<<<1, 256, 0, stream>>>(bsum, bofs, nullptr, nblk);
    k_scan2<<<nblk, 256, 0, stream>>>(tail_off, tail_cur, bofs, num_ent, nblk);
    // small scan: rcnt -> rel_off (+ rel_cur)
    k_scan<<<1, 1024, 0, stream>>>(rcnt, rel_off, rel_cur, num_rel);
    k_scatter_tail<<<512, 256, 0, stream>>>(heads, tails, edge_type, nE, num_ent, tail_cur, tail_edges);
    k_scatter_rel<<<NB, 256, 0, stream>>>(heads, tails, edge_type, nE, num_rel, rel_cur, rel_edges);
    int n4 = num_ent * 32;
    k_tobf16<<<(n4 + 255) / 256, 256, 0, stream>>>((const float4*)x0, x0h, n4);

    dim3 relgrid(num_rel, NS);
    int entgrid = (num_ent + 3) / 4;

    // ---- layer 1: x0h,pr0 -> x1h (bf16), pr1 ----
    k_ent<true><<<entgrid, 256, 0, stream>>>(x0h, pr0, tail_off, tail_edges, x1h, nullptr, num_ent);
    k_rel<<<relgrid, 256, 0, stream>>>(x0h, rel_off, rel_edges, rsumA);
    k_relfin_pr<<<num_rel, 64, 0, stream>>>(rsumA, rel_off, posmap, pr1, num_rel);

    // ---- layer 2: x1h,pr1 -> outputs (fp32) ----
    k_ent<false><<<entgrid, 256, 0, stream>>>(x1h, pr1, tail_off, tail_edges, nullptr, (float4*)x_out, num_ent);
    k_rel<<<relgrid, 256, 0, stream>>>(x1h, rel_off, rel_edges, rsumB);
    k_relfin<<<num_rel, 64, 0, stream>>>(rsumB, rel_off, topmap, r_out);
}